// Round 9
// baseline (190.610 us; speedup 1.0000x reference)
//
#include <hip/hip_runtime.h>

#define TN 80000
#define HD 128
#define NE 1280000
#define NB 8
#define NPG 10000
#define NG 8000

#define NBUCK 157           // buckets of 512 nodes (dst>>9)
#define BCAP  8704          // per-bucket record capacity (avg 8192)
#define CHUNK 4096
#define NCHUNK ((NE + CHUNK - 1) / CHUNK)   // 313
#define CONVX_BLK ((TN * HD / 8) / 256)     // 5000
#define CONVW_BLK ((HD * HD) / 256)         // 64

typedef __attribute__((ext_vector_type(8))) short short8;
typedef __attribute__((ext_vector_type(4))) float f32x4;

__device__ __forceinline__ unsigned short f2bf(float f){
  unsigned int u = __float_as_uint(f);
  u = u + 0x7FFFu + ((u >> 16) & 1u);
  return (unsigned short)(u >> 16);
}

__device__ __forceinline__ short8 pack_bf8(float4 a, float4 b){
  short8 o;
  o[0] = (short)f2bf(a.x); o[1] = (short)f2bf(a.y); o[2] = (short)f2bf(a.z); o[3] = (short)f2bf(a.w);
  o[4] = (short)f2bf(b.x); o[5] = (short)f2bf(b.y); o[6] = (short)f2bf(b.z); o[7] = (short)f2bf(b.w);
  return o;
}

// merged prep: [0,5000) x->bf16 ; [5000,5064) weights->bf16 ; 5064 colsums
__global__ __launch_bounds__(256) void k_prep(const float* __restrict__ x, unsigned short* __restrict__ xb,
    const float* __restrict__ W1, const float* __restrict__ W2,
    unsigned short* __restrict__ W1b, unsigned short* __restrict__ W2b,
    const float* __restrict__ Wrel2, const float* __restrict__ Wroot2, const float* __restrict__ brel2,
    float* __restrict__ crel, float* __restrict__ croot, float* __restrict__ cb){
  int b = blockIdx.x;
  if (b < CONVX_BLK){
    size_t i = ((size_t)b * 256 + threadIdx.x) * 8;
    float4 a0 = *(const float4*)(x + i), a1 = *(const float4*)(x + i + 4);
    *(short8*)(xb + i) = pack_bf8(a0, a1);
  } else if (b < CONVX_BLK + CONVW_BLK){
    int i = (b - CONVX_BLK) * 256 + threadIdx.x;
    W1b[i] = f2bf(W1[i]);
    W2b[i] = f2bf(W2[i]);
  } else {
    int k = threadIdx.x;
    if (k < HD){
      float a = 0.f, c = 0.f;
      for (int f = 0; f < HD; ++f){ a += Wrel2[f*HD + k]; c += Wroot2[f*HD + k]; }
      crel[k] = a; croot[k] = c;
      if (k == 0){ float s = 0.f; for (int f = 0; f < HD; ++f) s += brel2[f]; cb[0] = s; }
    }
  }
}

// ---- stage 1: chunk-sort 4096 edges by coarse bucket (dst>>9), grouped flush ----
// record: word0 = src | (dst&511)<<17 ; word1 = weight f32
__global__ __launch_bounds__(512) void k_cbin(const int* __restrict__ src, const int* __restrict__ dst,
                                              const float* __restrict__ ew,
                                              int* __restrict__ gcur, int2* __restrict__ rec){
  __shared__ int h[192];
  __shared__ int ex[192];
  __shared__ int2 grec[CHUNK];
  __shared__ unsigned char gcb[CHUNK];
  int t = threadIdx.x;
  int base = blockIdx.x * CHUNK;
  int n = NE - base; if (n > CHUNK) n = CHUNK;

  for (int i = t; i < 192; i += 512) h[i] = 0;
  __syncthreads();

  int pa[8]; float pw[8]; int pc[8];
  #pragma unroll
  for (int k = 0; k < 8; ++k){
    int idx = t + k * 512;
    if (idx < n){
      int e = base + idx;
      int d = dst[e];
      int cbk = d >> 9;
      pa[k] = src[e] | ((d & 511) << 17);
      pw[k] = ew[e];
      pc[k] = cbk;
      atomicAdd(&h[cbk], 1);
    } else pc[k] = -1;
  }
  __syncthreads();

  if (t < 64){
    int b0 = t * 3;
    int s = 0;
    #pragma unroll
    for (int j = 0; j < 3; ++j) s += h[b0 + j];
    int v = s;
    #pragma unroll
    for (int o = 1; o < 64; o <<= 1){ int q = __shfl_up(v, o); if (t >= o) v += q; }
    int run = v - s;
    #pragma unroll
    for (int j = 0; j < 3; ++j){ int q = h[b0 + j]; h[b0 + j] = run; ex[b0 + j] = run; run += q; }
  }
  __syncthreads();

  #pragma unroll
  for (int k = 0; k < 8; ++k){
    if (pc[k] >= 0){
      int p = atomicAdd(&h[pc[k]], 1);
      grec[p] = make_int2(pa[k], __float_as_int(pw[k]));
      gcb[p] = (unsigned char)pc[k];
    }
  }
  __syncthreads();

  for (int i = t; i < NBUCK; i += 512){
    int cnt = h[i] - ex[i];
    int go = 0;
    if (cnt > 0) go = atomicAdd(&gcur[i], cnt);
    ex[i] = i * BCAP + go - ex[i];
  }
  __syncthreads();

  for (int p = t; p < n; p += 512){
    int cbk = gcb[p];
    int ga = ex[cbk] + p;
    if (ga < (cbk + 1) * BCAP) rec[ga] = grec[p];
  }
}

// ---- stage 2: per-bucket counting sort by node (in LDS), emit start/cnt ----
__global__ __launch_bounds__(512) void k_nsort(const int* __restrict__ gcur, int2* __restrict__ rec,
                                               int* __restrict__ startp, int* __restrict__ cntp){
  __shared__ int cnt5[512], ex5[512], cur5[512];
  __shared__ int2 srec[BCAP];
  int t = threadIdx.x, b = blockIdx.x;
  int n = gcur[b]; if (n > BCAP) n = BCAP;
  size_t e0 = (size_t)b * BCAP;
  cnt5[t] = 0;
  __syncthreads();

  int2 rr[17];
  #pragma unroll
  for (int k = 0; k < 17; ++k){
    int i = t + k * 512;
    if (i < n){
      rr[k] = rec[e0 + i];
      atomicAdd(&cnt5[(rr[k].x >> 17) & 511], 1);
    }
  }
  __syncthreads();

  if (t < 64){
    int b0 = t * 8;
    int s = 0;
    #pragma unroll
    for (int j = 0; j < 8; ++j) s += cnt5[b0 + j];
    int v = s;
    #pragma unroll
    for (int o = 1; o < 64; o <<= 1){ int q = __shfl_up(v, o); if (t >= o) v += q; }
    int run = v - s;
    #pragma unroll
    for (int j = 0; j < 8; ++j){ int q = cnt5[b0 + j]; ex5[b0 + j] = run; cur5[b0 + j] = run; run += q; }
  }
  __syncthreads();

  #pragma unroll
  for (int k = 0; k < 17; ++k){
    int i = t + k * 512;
    if (i < n){
      int p = atomicAdd(&cur5[(rr[k].x >> 17) & 511], 1);
      srec[p] = rr[k];
    }
  }
  __syncthreads();

  #pragma unroll
  for (int k = 0; k < 17; ++k){
    int i = t + k * 512;
    if (i < n) rec[e0 + i] = srec[i];
  }
  int node = b * 512 + t;
  if (node < TN){
    startp[node] = (int)e0 + ex5[t];
    cntp[node] = cnt5[t];
  }
}

// ---- fused gather + node GEMM: block = 16 nodes ----
// phase 1: wave-per-node 8-deep gather -> z row in LDS (bf16, padded stride 136)
// phase 2: MFMA h = relu(z@W1^T + x@W2^T + b); u = h.crel; v = h.croot
__global__ __launch_bounds__(256) void k_gnode(const int* __restrict__ startp, const int* __restrict__ cntp,
    const int2* __restrict__ rec, const unsigned short* __restrict__ xb,
    const unsigned short* __restrict__ W1b, const unsigned short* __restrict__ W2b,
    const float* __restrict__ brel1, const float* __restrict__ crel, const float* __restrict__ croot,
    float* __restrict__ u, float* __restrict__ v){
  __shared__ unsigned short zl[16 * 136 + 8];
  __shared__ float up[4][16], vp[4][16];
  int t = threadIdx.x, w = t >> 6, lane = t & 63;
  int g = lane >> 4;      // edge group / K-slice
  int sl = lane & 15;     // 16B slot / node-in-tile
  int nb = blockIdx.x * 16;
  const uint4* xp = (const uint4*)xb;

  // ---- phase 1: each wave gathers 4 nodes ----
  for (int nn = 0; nn < 4; ++nn){
    int node = nb + w * 4 + nn;
    int e0 = startp[node], e1 = e0 + cntp[node];
    float acc[8] = {0,0,0,0,0,0,0,0};

    #define GSTEP(EBASE)                                                      \
    {                                                                         \
      int ee = (EBASE) + g;                                                   \
      bool val = ee < e1;                                                     \
      int2 r = rec[val ? ee : e0];                                            \
      float wgt = val ? __int_as_float(r.y) : 0.f;                            \
      uint4 p = xp[(size_t)(r.x & 0x1FFFF) * 16 + sl];                        \
      acc[0] += wgt * __uint_as_float(p.x << 16);                             \
      acc[1] += wgt * __uint_as_float(p.x & 0xFFFF0000u);                     \
      acc[2] += wgt * __uint_as_float(p.y << 16);                             \
      acc[3] += wgt * __uint_as_float(p.y & 0xFFFF0000u);                     \
      acc[4] += wgt * __uint_as_float(p.z << 16);                             \
      acc[5] += wgt * __uint_as_float(p.z & 0xFFFF0000u);                     \
      acc[6] += wgt * __uint_as_float(p.w << 16);                             \
      acc[7] += wgt * __uint_as_float(p.w & 0xFFFF0000u);                     \
    }

    int e = e0;
    for (; e + 8 <= e1; e += 8){
      GSTEP(e)
      GSTEP(e + 4)
    }
    if (e < e1){ GSTEP(e) if (e + 4 < e1){ GSTEP(e + 4) } }
    #undef GSTEP

    #pragma unroll
    for (int o = 16; o <= 32; o <<= 1){
      #pragma unroll
      for (int i = 0; i < 8; ++i) acc[i] += __shfl_xor(acc[i], o);
    }
    if (g == 0){
      uint4 o4;
      o4.x = ((unsigned)f2bf(acc[1]) << 16) | (unsigned)f2bf(acc[0]);
      o4.y = ((unsigned)f2bf(acc[3]) << 16) | (unsigned)f2bf(acc[2]);
      o4.z = ((unsigned)f2bf(acc[5]) << 16) | (unsigned)f2bf(acc[4]);
      o4.w = ((unsigned)f2bf(acc[7]) << 16) | (unsigned)f2bf(acc[6]);
      *(uint4*)(&zl[(w * 4 + nn) * 136 + sl * 8]) = o4;
    }
  }
  __syncthreads();

  // ---- phase 2: MFMA; wave w covers feature tiles t = 2w, 2w+1 ----
  {
    const unsigned short* xrow = xb + (size_t)(nb + sl) * HD + g * 8;
    short8 az[4], ax[4];
    #pragma unroll
    for (int kk = 0; kk < 4; ++kk){
      az[kk] = *(const short8*)(&zl[sl * 136 + g * 8 + kk * 32]);
      ax[kk] = *(const short8*)(xrow + kk * 32);
    }
    float usum[4] = {0,0,0,0}, vsum[4] = {0,0,0,0};
    #pragma unroll
    for (int tt = 2 * w; tt <= 2 * w + 1; ++tt){
      int kcol = tt * 16 + sl;
      const unsigned short* w1r = W1b + (size_t)kcol * HD + g * 8;
      const unsigned short* w2r = W2b + (size_t)kcol * HD + g * 8;
      f32x4 acc2 = {0.f, 0.f, 0.f, 0.f};
      #pragma unroll
      for (int kk = 0; kk < 4; ++kk)
        acc2 = __builtin_amdgcn_mfma_f32_16x16x32_bf16(az[kk], *(const short8*)(w1r + kk * 32), acc2, 0, 0, 0);
      #pragma unroll
      for (int kk = 0; kk < 4; ++kk)
        acc2 = __builtin_amdgcn_mfma_f32_16x16x32_bf16(ax[kk], *(const short8*)(w2r + kk * 32), acc2, 0, 0, 0);
      float bias = brel1[kcol], cr = crel[kcol], co = croot[kcol];
      #pragma unroll
      for (int r = 0; r < 4; ++r){
        float h = fmaxf(acc2[r] + bias, 0.f);
        usum[r] += h * cr;
        vsum[r] += h * co;
      }
    }
    #pragma unroll
    for (int o = 1; o < 16; o <<= 1){
      #pragma unroll
      for (int r = 0; r < 4; ++r){
        usum[r] += __shfl_xor(usum[r], o);
        vsum[r] += __shfl_xor(vsum[r], o);
      }
    }
    if (sl == 0){
      #pragma unroll
      for (int r = 0; r < 4; ++r){
        up[w][g * 4 + r] = usum[r];
        vp[w][g * 4 + r] = vsum[r];
      }
    }
  }
  __syncthreads();
  if (t < 16){
    u[nb + t] = (up[0][t] + up[1][t]) + (up[2][t] + up[3][t]);
    v[nb + t] = (vp[0][t] + vp[1][t]) + (vp[2][t] + vp[3][t]);
  }
}

// ---- layer-2 collapsed aggregation: thread per node via start/cnt ----
__global__ __launch_bounds__(256) void k_pool2(const int* __restrict__ startp, const int* __restrict__ cntp,
                                               const int2* __restrict__ rec,
                                               const float* __restrict__ u, float* __restrict__ sacc){
  int i = blockIdx.x * 256 + threadIdx.x;
  if (i >= TN) return;
  int e0 = startp[i], e1 = e0 + cntp[i];
  float s = 0.f;
  for (int e = e0; e < e1; ++e){
    int2 r = rec[e];
    s += __int_as_float(r.y) * u[r.x & 0x1FFFF];
  }
  sacc[i] = s;
}

__device__ __forceinline__ float blk_red_add(float x, float* red){
  #pragma unroll
  for (int o = 32; o > 0; o >>= 1) x += __shfl_xor(x, o);
  int wid = threadIdx.x >> 6, lane = threadIdx.x & 63;
  __syncthreads();
  if (lane == 0) red[wid] = x;
  __syncthreads();
  return (red[0] + red[1]) + (red[2] + red[3]);
}
__device__ __forceinline__ float blk_red_max(float x, float* red){
  #pragma unroll
  for (int o = 32; o > 0; o >>= 1) x = fmaxf(x, __shfl_xor(x, o));
  int wid = threadIdx.x >> 6, lane = threadIdx.x & 63;
  __syncthreads();
  if (lane == 0) red[wid] = x;
  __syncthreads();
  return fmaxf(fmaxf(red[0], red[1]), fmaxf(red[2], red[3]));
}

__global__ __launch_bounds__(256) void k_final(const float* __restrict__ s, const float* __restrict__ vv,
    const float* __restrict__ cbp, const float* __restrict__ gamma, const float* __restrict__ beta,
    float* __restrict__ out){
  __shared__ float t[NG];
  __shared__ float red[4];
  int b = blockIdx.x, tid = threadIdx.x;
  float cb = cbp[0];
  const float inv = 1.f / (float)HD;
  float lsum = 0.f, lsq = 0.f;
  for (int j = tid; j < NG; j += 256){
    float g = (s[b*NPG + j] + vv[b*NPG + j] + cb) * inv;
    t[j] = g; lsum += g; lsq += g * g;
  }
  float S1 = blk_red_add(lsum, red);
  float S2 = blk_red_add(lsq, red);
  float mu = S1 / (float)NG;
  float var = S2 / (float)NG - mu * mu;
  float rstd = rsqrtf(var + 1e-5f);
  float lmax = -3.4e38f;
  for (int j = tid; j < NG; j += 256){
    float tj = (t[j] - mu) * rstd * gamma[j] + beta[j];
    t[j] = tj; lmax = fmaxf(lmax, tj);
  }
  float M = blk_red_max(lmax, red);
  float lexp = 0.f;
  for (int j = tid; j < NG; j += 256) lexp += expf(t[j] - M);
  float S = blk_red_add(lexp, red);
  float lse = M + logf(S);
  for (int j = tid; j < NG; j += 256) out[b*NG + j] = t[j] - lse;
}

extern "C" void kernel_launch(void* const* d_in, const int* in_sizes, int n_in,
                              void* d_out, int out_size, void* d_ws, size_t ws_size,
                              hipStream_t stream){
  const float* x      = (const float*)d_in[0];
  const int*   ei     = (const int*)d_in[1];
  const float* ew     = (const float*)d_in[3];
  const float* Wrel1  = (const float*)d_in[4];
  const float* brel1  = (const float*)d_in[5];
  const float* Wroot1 = (const float*)d_in[6];
  const float* Wrel2  = (const float*)d_in[7];
  const float* brel2  = (const float*)d_in[8];
  const float* Wroot2 = (const float*)d_in[9];
  const float* gamma  = (const float*)d_in[10];
  const float* beta   = (const float*)d_in[11];
  const int*   src    = ei;
  const int*   dst    = ei + NE;

  char* ws = (char*)d_ws;
  size_t off_b = 0;
  auto alloc = [&](size_t bytes) -> char* {
    char* p = ws + off_b;
    off_b += (bytes + 511) & ~(size_t)511;
    return p;
  };
  unsigned short* xb    = (unsigned short*)alloc((size_t)TN * HD * 2);
  unsigned short* W1b   = (unsigned short*)alloc(HD * HD * 2);
  unsigned short* W2b   = (unsigned short*)alloc(HD * HD * 2);
  float*          crel  = (float*)alloc(HD * 4);
  float*          croot = (float*)alloc(HD * 4);
  float*          cbp   = (float*)alloc(4);
  float*          u     = (float*)alloc(TN * 4);
  float*          v     = (float*)alloc(TN * 4);
  float*          sacc  = (float*)alloc(TN * 4);
  int*            startp= (int*)alloc(TN * 4);
  int*            cntp  = (int*)alloc(TN * 4);
  int*            gcur  = (int*)alloc(NBUCK * 4);
  int2*           rec   = (int2*)alloc((size_t)NBUCK * BCAP * 8);

  hipMemsetAsync(gcur, 0, NBUCK * 4, stream);

  k_prep  <<<CONVX_BLK + CONVW_BLK + 1, 256, 0, stream>>>(x, xb, Wrel1, Wroot1, W1b, W2b,
                                                          Wrel2, Wroot2, brel2, crel, croot, cbp);
  k_cbin  <<<NCHUNK, 512, 0, stream>>>(src, dst, ew, gcur, rec);
  k_nsort <<<NBUCK, 512, 0, stream>>>(gcur, rec, startp, cntp);
  k_gnode <<<TN/16, 256, 0, stream>>>(startp, cntp, rec, xb, W1b, W2b, brel1, crel, croot, u, v);
  k_pool2 <<<(TN+255)/256, 256, 0, stream>>>(startp, cntp, rec, u, sacc);
  k_final <<<NB, 256, 0, stream>>>(sacc, v, cbp, gamma, beta, (float*)d_out);
}

// Round 10
// 176.353 us; speedup vs baseline: 1.0808x; 1.0808x over previous
//
#include <hip/hip_runtime.h>

#define TN 80000
#define HD 128
#define NE 1280000
#define NB 8
#define NPG 10000
#define NG 8000

#define NBUCK 157           // buckets of 512 nodes (dst>>9)
#define BCAP  8704          // per-bucket record capacity (avg 8192)
#define CHUNK 4096
#define NCHUNK ((NE + CHUNK - 1) / CHUNK)   // 313
#define CONVX_BLK ((TN * HD / 8) / 256)     // 5000
#define CONVW_BLK ((HD * HD) / 256)         // 64

typedef __attribute__((ext_vector_type(8))) short short8;
typedef __attribute__((ext_vector_type(4))) float f32x4;

__device__ __forceinline__ unsigned short f2bf(float f){
  unsigned int u = __float_as_uint(f);
  u = u + 0x7FFFu + ((u >> 16) & 1u);
  return (unsigned short)(u >> 16);
}

__device__ __forceinline__ short8 pack_bf8(float4 a, float4 b){
  short8 o;
  o[0] = (short)f2bf(a.x); o[1] = (short)f2bf(a.y); o[2] = (short)f2bf(a.z); o[3] = (short)f2bf(a.w);
  o[4] = (short)f2bf(b.x); o[5] = (short)f2bf(b.y); o[6] = (short)f2bf(b.z); o[7] = (short)f2bf(b.w);
  return o;
}

// merged prep: [0,5000) x->bf16 ; [5000,5064) weights->bf16 ; 5064 colsums
__global__ __launch_bounds__(256) void k_prep(const float* __restrict__ x, unsigned short* __restrict__ xb,
    const float* __restrict__ W1, const float* __restrict__ W2,
    unsigned short* __restrict__ W1b, unsigned short* __restrict__ W2b,
    const float* __restrict__ Wrel2, const float* __restrict__ Wroot2, const float* __restrict__ brel2,
    float* __restrict__ crel, float* __restrict__ croot, float* __restrict__ cb){
  int b = blockIdx.x;
  if (b < CONVX_BLK){
    size_t i = ((size_t)b * 256 + threadIdx.x) * 8;
    float4 a0 = *(const float4*)(x + i), a1 = *(const float4*)(x + i + 4);
    *(short8*)(xb + i) = pack_bf8(a0, a1);
  } else if (b < CONVX_BLK + CONVW_BLK){
    int i = (b - CONVX_BLK) * 256 + threadIdx.x;
    W1b[i] = f2bf(W1[i]);
    W2b[i] = f2bf(W2[i]);
  } else {
    int k = threadIdx.x;
    if (k < HD){
      float a = 0.f, c = 0.f;
      for (int f = 0; f < HD; ++f){ a += Wrel2[f*HD + k]; c += Wroot2[f*HD + k]; }
      crel[k] = a; croot[k] = c;
      if (k == 0){ float s = 0.f; for (int f = 0; f < HD; ++f) s += brel2[f]; cb[0] = s; }
    }
  }
}

// ---- stage 1: chunk-sort 4096 edges by coarse bucket (dst>>9), grouped flush ----
// record: word0 = src | (dst&511)<<17 ; word1 = weight f32
__global__ __launch_bounds__(512) void k_cbin(const int* __restrict__ src, const int* __restrict__ dst,
                                              const float* __restrict__ ew,
                                              int* __restrict__ gcur, int2* __restrict__ rec){
  __shared__ int h[192];
  __shared__ int ex[192];
  __shared__ int2 grec[CHUNK];
  __shared__ unsigned char gcb[CHUNK];
  int t = threadIdx.x;
  int base = blockIdx.x * CHUNK;
  int n = NE - base; if (n > CHUNK) n = CHUNK;

  for (int i = t; i < 192; i += 512) h[i] = 0;
  __syncthreads();

  int pa[8]; float pw[8]; int pc[8];
  #pragma unroll
  for (int k = 0; k < 8; ++k){
    int idx = t + k * 512;
    if (idx < n){
      int e = base + idx;
      int d = dst[e];
      int cbk = d >> 9;
      pa[k] = src[e] | ((d & 511) << 17);
      pw[k] = ew[e];
      pc[k] = cbk;
      atomicAdd(&h[cbk], 1);
    } else pc[k] = -1;
  }
  __syncthreads();

  if (t < 64){
    int b0 = t * 3;
    int s = 0;
    #pragma unroll
    for (int j = 0; j < 3; ++j) s += h[b0 + j];
    int v = s;
    #pragma unroll
    for (int o = 1; o < 64; o <<= 1){ int q = __shfl_up(v, o); if (t >= o) v += q; }
    int run = v - s;
    #pragma unroll
    for (int j = 0; j < 3; ++j){ int q = h[b0 + j]; h[b0 + j] = run; ex[b0 + j] = run; run += q; }
  }
  __syncthreads();

  #pragma unroll
  for (int k = 0; k < 8; ++k){
    if (pc[k] >= 0){
      int p = atomicAdd(&h[pc[k]], 1);
      grec[p] = make_int2(pa[k], __float_as_int(pw[k]));
      gcb[p] = (unsigned char)pc[k];
    }
  }
  __syncthreads();

  for (int i = t; i < NBUCK; i += 512){
    int cnt = h[i] - ex[i];
    int go = 0;
    if (cnt > 0) go = atomicAdd(&gcur[i], cnt);
    ex[i] = i * BCAP + go - ex[i];
  }
  __syncthreads();

  for (int p = t; p < n; p += 512){
    int cbk = gcb[p];
    int ga = ex[cbk] + p;
    if (ga < (cbk + 1) * BCAP) rec[ga] = grec[p];
  }
}

// ---- stage 2: per-bucket counting sort by node (in LDS), emit start/cnt ----
__global__ __launch_bounds__(512) void k_nsort(const int* __restrict__ gcur, int2* __restrict__ rec,
                                               int* __restrict__ startp, int* __restrict__ cntp){
  __shared__ int cnt5[512], ex5[512], cur5[512];
  __shared__ int2 srec[BCAP];
  int t = threadIdx.x, b = blockIdx.x;
  int n = gcur[b]; if (n > BCAP) n = BCAP;
  size_t e0 = (size_t)b * BCAP;
  cnt5[t] = 0;
  __syncthreads();

  int2 rr[17];
  #pragma unroll
  for (int k = 0; k < 17; ++k){
    int i = t + k * 512;
    if (i < n){
      rr[k] = rec[e0 + i];
      atomicAdd(&cnt5[(rr[k].x >> 17) & 511], 1);
    }
  }
  __syncthreads();

  if (t < 64){
    int b0 = t * 8;
    int s = 0;
    #pragma unroll
    for (int j = 0; j < 8; ++j) s += cnt5[b0 + j];
    int v = s;
    #pragma unroll
    for (int o = 1; o < 64; o <<= 1){ int q = __shfl_up(v, o); if (t >= o) v += q; }
    int run = v - s;
    #pragma unroll
    for (int j = 0; j < 8; ++j){ int q = cnt5[b0 + j]; ex5[b0 + j] = run; cur5[b0 + j] = run; run += q; }
  }
  __syncthreads();

  #pragma unroll
  for (int k = 0; k < 17; ++k){
    int i = t + k * 512;
    if (i < n){
      int p = atomicAdd(&cur5[(rr[k].x >> 17) & 511], 1);
      srec[p] = rr[k];
    }
  }
  __syncthreads();

  #pragma unroll
  for (int k = 0; k < 17; ++k){
    int i = t + k * 512;
    if (i < n) rec[e0 + i] = srec[i];
  }
  int node = b * 512 + t;
  if (node < TN){
    startp[node] = (int)e0 + ex5[t];
    cntp[node] = cnt5[t];
  }
}

// ---- layer-1 aggregation: one wave per node, explicit 8-edge dual-load pipeline ----
__global__ __launch_bounds__(256) void k_gather(const int* __restrict__ startp, const int* __restrict__ cntp,
                                                const int2* __restrict__ rec,
                                                const unsigned short* __restrict__ xb, unsigned short* __restrict__ zb){
  int wid = threadIdx.x >> 6, lane = threadIdx.x & 63;
  int node = blockIdx.x * 4 + wid;
  int e0 = startp[node], e1 = e0 + cntp[node];
  int g  = lane >> 4;     // edge group 0..3
  int sl = lane & 15;     // 16B slot within row
  const uint4* xp = (const uint4*)xb;   // row = 16 uint4

  float acc[8] = {0,0,0,0,0,0,0,0};

  #define FMA8(P, W)                                                          \
    acc[0] += (W) * __uint_as_float((P).x << 16);                             \
    acc[1] += (W) * __uint_as_float((P).x & 0xFFFF0000u);                     \
    acc[2] += (W) * __uint_as_float((P).y << 16);                             \
    acc[3] += (W) * __uint_as_float((P).y & 0xFFFF0000u);                     \
    acc[4] += (W) * __uint_as_float((P).z << 16);                             \
    acc[5] += (W) * __uint_as_float((P).z & 0xFFFF0000u);                     \
    acc[6] += (W) * __uint_as_float((P).w << 16);                             \
    acc[7] += (W) * __uint_as_float((P).w & 0xFFFF0000u);

  int e = e0;
  for (; e + 8 <= e1; e += 8){
    // issue all 4 loads before any FMA: 2 records, then 2 rows
    int2 r0 = rec[e + g];
    int2 r1 = rec[e + 4 + g];
    uint4 p0 = xp[(size_t)(r0.x & 0x1FFFF) * 16 + sl];
    uint4 p1 = xp[(size_t)(r1.x & 0x1FFFF) * 16 + sl];
    float w0 = __int_as_float(r0.y);
    float w1 = __int_as_float(r1.y);
    FMA8(p0, w0)
    FMA8(p1, w1)
  }
  // tail (predicated, weight 0 for pad lanes)
  if (e < e1){
    int ee = e + g;
    bool v0 = ee < e1;
    int2 r0 = rec[v0 ? ee : e0];
    int ee1 = e + 4 + g;
    bool v1 = ee1 < e1;
    int2 r1 = rec[v1 ? ee1 : e0];
    uint4 p0 = xp[(size_t)(r0.x & 0x1FFFF) * 16 + sl];
    uint4 p1 = xp[(size_t)(r1.x & 0x1FFFF) * 16 + sl];
    float w0 = v0 ? __int_as_float(r0.y) : 0.f;
    float w1 = v1 ? __int_as_float(r1.y) : 0.f;
    FMA8(p0, w0)
    FMA8(p1, w1)
  }
  #undef FMA8

  #pragma unroll
  for (int o = 16; o <= 32; o <<= 1){
    #pragma unroll
    for (int i = 0; i < 8; ++i) acc[i] += __shfl_xor(acc[i], o);
  }
  if (g == 0){
    uint4 o4;
    o4.x = ((unsigned)f2bf(acc[1]) << 16) | (unsigned)f2bf(acc[0]);
    o4.y = ((unsigned)f2bf(acc[3]) << 16) | (unsigned)f2bf(acc[2]);
    o4.z = ((unsigned)f2bf(acc[5]) << 16) | (unsigned)f2bf(acc[4]);
    o4.w = ((unsigned)f2bf(acc[7]) << 16) | (unsigned)f2bf(acc[6]);
    ((uint4*)zb)[(size_t)node * 16 + sl] = o4;
  }
}

// Fused: h = relu(z@W1^T + x@W2^T + b); u = h . crel; v = h . croot  (bf16 inputs)
__global__ __launch_bounds__(256) void k_node(const unsigned short* __restrict__ zb, const unsigned short* __restrict__ xb,
    const unsigned short* __restrict__ W1b, const unsigned short* __restrict__ W2b,
    const float* __restrict__ brel1, const float* __restrict__ crel, const float* __restrict__ croot,
    float* __restrict__ u, float* __restrict__ v){
  int wid = threadIdx.x >> 6;
  int lane = threadIdx.x & 63;
  int l15 = lane & 15;
  int g4 = lane >> 4;
  int nb = blockIdx.x * 64 + wid * 16;

  const unsigned short* zrow = zb + (size_t)(nb + l15) * HD + g4 * 8;
  const unsigned short* xrow = xb + (size_t)(nb + l15) * HD + g4 * 8;
  short8 az[4], ax[4];
  #pragma unroll
  for (int kk = 0; kk < 4; ++kk){
    az[kk] = *(const short8*)(zrow + kk * 32);
    ax[kk] = *(const short8*)(xrow + kk * 32);
  }

  float usum[4] = {0,0,0,0}, vsum[4] = {0,0,0,0};
  #pragma unroll
  for (int t = 0; t < 8; ++t){
    int kcol = t * 16 + l15;
    const unsigned short* w1r = W1b + (size_t)kcol * HD + g4 * 8;
    const unsigned short* w2r = W2b + (size_t)kcol * HD + g4 * 8;
    f32x4 acc = {0.f, 0.f, 0.f, 0.f};
    #pragma unroll
    for (int kk = 0; kk < 4; ++kk)
      acc = __builtin_amdgcn_mfma_f32_16x16x32_bf16(az[kk], *(const short8*)(w1r + kk * 32), acc, 0, 0, 0);
    #pragma unroll
    for (int kk = 0; kk < 4; ++kk)
      acc = __builtin_amdgcn_mfma_f32_16x16x32_bf16(ax[kk], *(const short8*)(w2r + kk * 32), acc, 0, 0, 0);
    float bias = brel1[kcol], cr = crel[kcol], co = croot[kcol];
    #pragma unroll
    for (int r = 0; r < 4; ++r){
      float h = fmaxf(acc[r] + bias, 0.f);
      usum[r] += h * cr;
      vsum[r] += h * co;
    }
  }
  #pragma unroll
  for (int o = 1; o < 16; o <<= 1){
    #pragma unroll
    for (int r = 0; r < 4; ++r){
      usum[r] += __shfl_xor(usum[r], o);
      vsum[r] += __shfl_xor(vsum[r], o);
    }
  }
  if (l15 == 0){
    #pragma unroll
    for (int r = 0; r < 4; ++r){
      int node = nb + g4 * 4 + r;
      u[node] = usum[r];
      v[node] = vsum[r];
    }
  }
}

// ---- layer-2 collapsed aggregation: thread per node via start/cnt ----
// only nodes with (node % NPG) < NG are ever read by k_final
__global__ __launch_bounds__(256) void k_pool2(const int* __restrict__ startp, const int* __restrict__ cntp,
                                               const int2* __restrict__ rec,
                                               const float* __restrict__ u, float* __restrict__ sacc){
  int i = blockIdx.x * 256 + threadIdx.x;
  if (i >= TN) return;
  if (i % NPG >= NG) return;
  int e0 = startp[i], e1 = e0 + cntp[i];
  float s = 0.f;
  for (int e = e0; e < e1; ++e){
    int2 r = rec[e];
    s += __int_as_float(r.y) * u[r.x & 0x1FFFF];
  }
  sacc[i] = s;
}

__device__ __forceinline__ float blk_red_add(float x, float* red){
  #pragma unroll
  for (int o = 32; o > 0; o >>= 1) x += __shfl_xor(x, o);
  int wid = threadIdx.x >> 6, lane = threadIdx.x & 63;
  __syncthreads();
  if (lane == 0) red[wid] = x;
  __syncthreads();
  return (red[0] + red[1]) + (red[2] + red[3]);
}
__device__ __forceinline__ float blk_red_max(float x, float* red){
  #pragma unroll
  for (int o = 32; o > 0; o >>= 1) x = fmaxf(x, __shfl_xor(x, o));
  int wid = threadIdx.x >> 6, lane = threadIdx.x & 63;
  __syncthreads();
  if (lane == 0) red[wid] = x;
  __syncthreads();
  return fmaxf(fmaxf(red[0], red[1]), fmaxf(red[2], red[3]));
}

__global__ __launch_bounds__(256) void k_final(const float* __restrict__ s, const float* __restrict__ vv,
    const float* __restrict__ cbp, const float* __restrict__ gamma, const float* __restrict__ beta,
    float* __restrict__ out){
  __shared__ float t[NG];
  __shared__ float red[4];
  int b = blockIdx.x, tid = threadIdx.x;
  float cb = cbp[0];
  const float inv = 1.f / (float)HD;
  float lsum = 0.f, lsq = 0.f;
  for (int j = tid; j < NG; j += 256){
    float g = (s[b*NPG + j] + vv[b*NPG + j] + cb) * inv;
    t[j] = g; lsum += g; lsq += g * g;
  }
  float S1 = blk_red_add(lsum, red);
  float S2 = blk_red_add(lsq, red);
  float mu = S1 / (float)NG;
  float var = S2 / (float)NG - mu * mu;
  float rstd = rsqrtf(var + 1e-5f);
  float lmax = -3.4e38f;
  for (int j = tid; j < NG; j += 256){
    float tj = (t[j] - mu) * rstd * gamma[j] + beta[j];
    t[j] = tj; lmax = fmaxf(lmax, tj);
  }
  float M = blk_red_max(lmax, red);
  float lexp = 0.f;
  for (int j = tid; j < NG; j += 256) lexp += expf(t[j] - M);
  float S = blk_red_add(lexp, red);
  float lse = M + logf(S);
  for (int j = tid; j < NG; j += 256) out[b*NG + j] = t[j] - lse;
}

extern "C" void kernel_launch(void* const* d_in, const int* in_sizes, int n_in,
                              void* d_out, int out_size, void* d_ws, size_t ws_size,
                              hipStream_t stream){
  const float* x      = (const float*)d_in[0];
  const int*   ei     = (const int*)d_in[1];
  const float* ew     = (const float*)d_in[3];
  const float* Wrel1  = (const float*)d_in[4];
  const float* brel1  = (const float*)d_in[5];
  const float* Wroot1 = (const float*)d_in[6];
  const float* Wrel2  = (const float*)d_in[7];
  const float* brel2  = (const float*)d_in[8];
  const float* Wroot2 = (const float*)d_in[9];
  const float* gamma  = (const float*)d_in[10];
  const float* beta   = (const float*)d_in[11];
  const int*   src    = ei;
  const int*   dst    = ei + NE;

  char* ws = (char*)d_ws;
  size_t off_b = 0;
  auto alloc = [&](size_t bytes) -> char* {
    char* p = ws + off_b;
    off_b += (bytes + 511) & ~(size_t)511;
    return p;
  };
  unsigned short* xb    = (unsigned short*)alloc((size_t)TN * HD * 2);
  unsigned short* zb    = (unsigned short*)alloc((size_t)TN * HD * 2);
  unsigned short* W1b   = (unsigned short*)alloc(HD * HD * 2);
  unsigned short* W2b   = (unsigned short*)alloc(HD * HD * 2);
  float*          crel  = (float*)alloc(HD * 4);
  float*          croot = (float*)alloc(HD * 4);
  float*          cbp   = (float*)alloc(4);
  float*          u     = (float*)alloc(TN * 4);
  float*          v     = (float*)alloc(TN * 4);
  float*          sacc  = (float*)alloc(TN * 4);
  int*            startp= (int*)alloc(TN * 4);
  int*            cntp  = (int*)alloc(TN * 4);
  int*            gcur  = (int*)alloc(NBUCK * 4);
  int2*           rec   = (int2*)alloc((size_t)NBUCK * BCAP * 8);

  hipMemsetAsync(gcur, 0, NBUCK * 4, stream);

  k_prep  <<<CONVX_BLK + CONVW_BLK + 1, 256, 0, stream>>>(x, xb, Wrel1, Wroot1, W1b, W2b,
                                                          Wrel2, Wroot2, brel2, crel, croot, cbp);
  k_cbin  <<<NCHUNK, 512, 0, stream>>>(src, dst, ew, gcur, rec);
  k_nsort <<<NBUCK, 512, 0, stream>>>(gcur, rec, startp, cntp);
  k_gather<<<TN/4, 256, 0, stream>>>(startp, cntp, rec, xb, zb);
  k_node  <<<TN/64, 256, 0, stream>>>(zb, xb, W1b, W2b, brel1, crel, croot, u, v);
  k_pool2 <<<(TN+255)/256, 256, 0, stream>>>(startp, cntp, rec, u, sacc);
  k_final <<<NB, 256, 0, stream>>>(sacc, v, cbp, gamma, beta, (float*)d_out);
}

// Round 11
// 151.238 us; speedup vs baseline: 1.2603x; 1.1661x over previous
//
#include <hip/hip_runtime.h>

#define TN 80000
#define HD 128
#define NE 1280000
#define NB 8
#define NPG 10000
#define NG 8000

#define NBUCK 313           // buckets of 256 nodes (dst>>8)
#define BCAP  4608          // per-bucket record capacity (avg 4090, +8 sigma)
#define CHUNK 4096
#define NCHUNK ((NE + CHUNK - 1) / CHUNK)   // 313

#define PX_BLK 2500         // x->bf16: 2500 blocks x 512 thr x 8 elems
#define PW_BLK 32           // weights->bf16: 16384 elems / 512
#define PREP_BLK (PX_BLK + PW_BLK + 1)      // 2533

typedef __attribute__((ext_vector_type(8))) short short8;
typedef __attribute__((ext_vector_type(4))) float f32x4;

__device__ __forceinline__ unsigned short f2bf(float f){
  unsigned int u = __float_as_uint(f);
  u = u + 0x7FFFu + ((u >> 16) & 1u);
  return (unsigned short)(u >> 16);
}

__device__ __forceinline__ short8 pack_bf8(float4 a, float4 b){
  short8 o;
  o[0] = (short)f2bf(a.x); o[1] = (short)f2bf(a.y); o[2] = (short)f2bf(a.z); o[3] = (short)f2bf(a.w);
  o[4] = (short)f2bf(b.x); o[5] = (short)f2bf(b.y); o[6] = (short)f2bf(b.z); o[7] = (short)f2bf(b.w);
  return o;
}

// merged prep + coarse binning, block-range dispatch, 512 threads
// [0,PX_BLK): x->bf16 ; [PX_BLK,+PW_BLK): weights ; PX_BLK+PW_BLK: colsums ;
// [PREP_BLK, PREP_BLK+NCHUNK): chunk-sort 4096 edges by bucket (dst>>8), grouped flush
// record: word0 = src | (dst&255)<<17 ; word1 = weight f32
__global__ __launch_bounds__(512) void k_prepbin(const float* __restrict__ x, unsigned short* __restrict__ xb,
    const float* __restrict__ W1, const float* __restrict__ W2,
    unsigned short* __restrict__ W1b, unsigned short* __restrict__ W2b,
    const float* __restrict__ Wrel2, const float* __restrict__ Wroot2, const float* __restrict__ brel2,
    float* __restrict__ crel, float* __restrict__ croot, float* __restrict__ cb,
    const int* __restrict__ src, const int* __restrict__ dst, const float* __restrict__ ew,
    int* __restrict__ gcur, int2* __restrict__ rec){
  int b = blockIdx.x;
  int t = threadIdx.x;
  if (b < PX_BLK){
    size_t i = ((size_t)b * 512 + t) * 8;
    float4 a0 = *(const float4*)(x + i), a1 = *(const float4*)(x + i + 4);
    *(short8*)(xb + i) = pack_bf8(a0, a1);
    return;
  }
  if (b < PX_BLK + PW_BLK){
    int i = (b - PX_BLK) * 512 + t;
    W1b[i] = f2bf(W1[i]);
    W2b[i] = f2bf(W2[i]);
    return;
  }
  if (b == PX_BLK + PW_BLK){
    int k = t;
    if (k < HD){
      float a = 0.f, c = 0.f;
      for (int f = 0; f < HD; ++f){ a += Wrel2[f*HD + k]; c += Wroot2[f*HD + k]; }
      crel[k] = a; croot[k] = c;
      if (k == 0){ float s = 0.f; for (int f = 0; f < HD; ++f) s += brel2[f]; cb[0] = s; }
    }
    return;
  }
  // ---- cbin part ----
  __shared__ int h[320];
  __shared__ int ex[320];
  __shared__ int2 grec[CHUNK];          // 32 KB
  __shared__ unsigned short gcb[CHUNK]; // 8 KB
  int base = (b - PREP_BLK) * CHUNK;
  int n = NE - base; if (n > CHUNK) n = CHUNK;

  for (int i = t; i < 320; i += 512) h[i] = 0;
  __syncthreads();

  int pa[8]; float pw[8]; int pc[8];
  #pragma unroll
  for (int k = 0; k < 8; ++k){
    int idx = t + k * 512;
    if (idx < n){
      int e = base + idx;
      int d = dst[e];
      int cbk = d >> 8;
      pa[k] = src[e] | ((d & 255) << 17);
      pw[k] = ew[e];
      pc[k] = cbk;
      atomicAdd(&h[cbk], 1);
    } else pc[k] = -1;
  }
  __syncthreads();

  // exclusive scan of 320 counters by wave 0 (5 slots/lane + shfl scan)
  if (t < 64){
    int b0 = t * 5;
    int s = 0;
    #pragma unroll
    for (int j = 0; j < 5; ++j) s += h[b0 + j];
    int v = s;
    #pragma unroll
    for (int o = 1; o < 64; o <<= 1){ int q = __shfl_up(v, o); if (t >= o) v += q; }
    int run = v - s;
    #pragma unroll
    for (int j = 0; j < 5; ++j){ int q = h[b0 + j]; h[b0 + j] = run; ex[b0 + j] = run; run += q; }
  }
  __syncthreads();

  #pragma unroll
  for (int k = 0; k < 8; ++k){
    if (pc[k] >= 0){
      int p = atomicAdd(&h[pc[k]], 1);
      grec[p] = make_int2(pa[k], __float_as_int(pw[k]));
      gcb[p] = (unsigned short)pc[k];
    }
  }
  __syncthreads();

  for (int i = t; i < NBUCK; i += 512){
    int cnt = h[i] - ex[i];
    int go = 0;
    if (cnt > 0) go = atomicAdd(&gcur[i], cnt);
    ex[i] = i * BCAP + go - ex[i];
  }
  __syncthreads();

  for (int p = t; p < n; p += 512){
    int cbk = gcb[p];
    int ga = ex[cbk] + p;
    if (ga < (cbk + 1) * BCAP) rec[ga] = grec[p];
  }
}

// ---- stage 2: per-bucket counting sort by node (in LDS), emit start/cnt ----
__global__ __launch_bounds__(512) void k_nsort(const int* __restrict__ gcur, int2* __restrict__ rec,
                                               int* __restrict__ startp, int* __restrict__ cntp){
  __shared__ int cnt5[256], ex5[256], cur5[256];
  __shared__ int2 srec[BCAP];          // 36 KB
  int t = threadIdx.x, b = blockIdx.x;
  int n = gcur[b]; if (n > BCAP) n = BCAP;
  size_t e0 = (size_t)b * BCAP;
  if (t < 256) cnt5[t] = 0;
  __syncthreads();

  int2 rr[9];                           // ceil(BCAP/512) == 9
  #pragma unroll
  for (int k = 0; k < 9; ++k){
    int i = t + k * 512;
    if (i < n){
      rr[k] = rec[e0 + i];
      atomicAdd(&cnt5[(rr[k].x >> 17) & 255], 1);
    }
  }
  __syncthreads();

  if (t < 64){
    int b0 = t * 4;
    int s = 0;
    #pragma unroll
    for (int j = 0; j < 4; ++j) s += cnt5[b0 + j];
    int v = s;
    #pragma unroll
    for (int o = 1; o < 64; o <<= 1){ int q = __shfl_up(v, o); if (t >= o) v += q; }
    int run = v - s;
    #pragma unroll
    for (int j = 0; j < 4; ++j){ int q = cnt5[b0 + j]; ex5[b0 + j] = run; cur5[b0 + j] = run; run += q; }
  }
  __syncthreads();

  #pragma unroll
  for (int k = 0; k < 9; ++k){
    int i = t + k * 512;
    if (i < n){
      int p = atomicAdd(&cur5[(rr[k].x >> 17) & 255], 1);
      srec[p] = rr[k];
    }
  }
  __syncthreads();

  #pragma unroll
  for (int k = 0; k < 9; ++k){
    int i = t + k * 512;
    if (i < n) rec[e0 + i] = srec[i];
  }
  if (t < 256){
    int node = b * 256 + t;
    if (node < TN){
      startp[node] = (int)e0 + ex5[t];
      cntp[node] = cnt5[t];
    }
  }
}

// ---- layer-1 aggregation: one wave per node, explicit 8-edge dual-load pipeline ----
__global__ __launch_bounds__(256) void k_gather(const int* __restrict__ startp, const int* __restrict__ cntp,
                                                const int2* __restrict__ rec,
                                                const unsigned short* __restrict__ xb, unsigned short* __restrict__ zb){
  int wid = threadIdx.x >> 6, lane = threadIdx.x & 63;
  int node = blockIdx.x * 4 + wid;
  int e0 = startp[node], e1 = e0 + cntp[node];
  int g  = lane >> 4;     // edge group 0..3
  int sl = lane & 15;     // 16B slot within row
  const uint4* xp = (const uint4*)xb;   // row = 16 uint4

  float acc[8] = {0,0,0,0,0,0,0,0};

  #define FMA8(P, W)                                                          \
    acc[0] += (W) * __uint_as_float((P).x << 16);                             \
    acc[1] += (W) * __uint_as_float((P).x & 0xFFFF0000u);                     \
    acc[2] += (W) * __uint_as_float((P).y << 16);                             \
    acc[3] += (W) * __uint_as_float((P).y & 0xFFFF0000u);                     \
    acc[4] += (W) * __uint_as_float((P).z << 16);                             \
    acc[5] += (W) * __uint_as_float((P).z & 0xFFFF0000u);                     \
    acc[6] += (W) * __uint_as_float((P).w << 16);                             \
    acc[7] += (W) * __uint_as_float((P).w & 0xFFFF0000u);

  int e = e0;
  for (; e + 8 <= e1; e += 8){
    int2 r0 = rec[e + g];
    int2 r1 = rec[e + 4 + g];
    uint4 p0 = xp[(size_t)(r0.x & 0x1FFFF) * 16 + sl];
    uint4 p1 = xp[(size_t)(r1.x & 0x1FFFF) * 16 + sl];
    float w0 = __int_as_float(r0.y);
    float w1 = __int_as_float(r1.y);
    FMA8(p0, w0)
    FMA8(p1, w1)
  }
  if (e < e1){
    int ee = e + g;
    bool v0 = ee < e1;
    int2 r0 = rec[v0 ? ee : e0];
    int ee1 = e + 4 + g;
    bool v1 = ee1 < e1;
    int2 r1 = rec[v1 ? ee1 : e0];
    uint4 p0 = xp[(size_t)(r0.x & 0x1FFFF) * 16 + sl];
    uint4 p1 = xp[(size_t)(r1.x & 0x1FFFF) * 16 + sl];
    float w0 = v0 ? __int_as_float(r0.y) : 0.f;
    float w1 = v1 ? __int_as_float(r1.y) : 0.f;
    FMA8(p0, w0)
    FMA8(p1, w1)
  }
  #undef FMA8

  #pragma unroll
  for (int o = 16; o <= 32; o <<= 1){
    #pragma unroll
    for (int i = 0; i < 8; ++i) acc[i] += __shfl_xor(acc[i], o);
  }
  if (g == 0){
    uint4 o4;
    o4.x = ((unsigned)f2bf(acc[1]) << 16) | (unsigned)f2bf(acc[0]);
    o4.y = ((unsigned)f2bf(acc[3]) << 16) | (unsigned)f2bf(acc[2]);
    o4.z = ((unsigned)f2bf(acc[5]) << 16) | (unsigned)f2bf(acc[4]);
    o4.w = ((unsigned)f2bf(acc[7]) << 16) | (unsigned)f2bf(acc[6]);
    ((uint4*)zb)[(size_t)node * 16 + sl] = o4;
  }
}

// Fused: h = relu(z@W1^T + x@W2^T + b); u = h . crel; v = h . croot  (bf16 inputs)
__global__ __launch_bounds__(256) void k_node(const unsigned short* __restrict__ zb, const unsigned short* __restrict__ xb,
    const unsigned short* __restrict__ W1b, const unsigned short* __restrict__ W2b,
    const float* __restrict__ brel1, const float* __restrict__ crel, const float* __restrict__ croot,
    float* __restrict__ u, float* __restrict__ v){
  int wid = threadIdx.x >> 6;
  int lane = threadIdx.x & 63;
  int l15 = lane & 15;
  int g4 = lane >> 4;
  int nb = blockIdx.x * 64 + wid * 16;

  const unsigned short* zrow = zb + (size_t)(nb + l15) * HD + g4 * 8;
  const unsigned short* xrow = xb + (size_t)(nb + l15) * HD + g4 * 8;
  short8 az[4], ax[4];
  #pragma unroll
  for (int kk = 0; kk < 4; ++kk){
    az[kk] = *(const short8*)(zrow + kk * 32);
    ax[kk] = *(const short8*)(xrow + kk * 32);
  }

  float usum[4] = {0,0,0,0}, vsum[4] = {0,0,0,0};
  #pragma unroll
  for (int t = 0; t < 8; ++t){
    int kcol = t * 16 + l15;
    const unsigned short* w1r = W1b + (size_t)kcol * HD + g4 * 8;
    const unsigned short* w2r = W2b + (size_t)kcol * HD + g4 * 8;
    f32x4 acc = {0.f, 0.f, 0.f, 0.f};
    #pragma unroll
    for (int kk = 0; kk < 4; ++kk)
      acc = __builtin_amdgcn_mfma_f32_16x16x32_bf16(az[kk], *(const short8*)(w1r + kk * 32), acc, 0, 0, 0);
    #pragma unroll
    for (int kk = 0; kk < 4; ++kk)
      acc = __builtin_amdgcn_mfma_f32_16x16x32_bf16(ax[kk], *(const short8*)(w2r + kk * 32), acc, 0, 0, 0);
    float bias = brel1[kcol], cr = crel[kcol], co = croot[kcol];
    #pragma unroll
    for (int r = 0; r < 4; ++r){
      float h = fmaxf(acc[r] + bias, 0.f);
      usum[r] += h * cr;
      vsum[r] += h * co;
    }
  }
  #pragma unroll
  for (int o = 1; o < 16; o <<= 1){
    #pragma unroll
    for (int r = 0; r < 4; ++r){
      usum[r] += __shfl_xor(usum[r], o);
      vsum[r] += __shfl_xor(vsum[r], o);
    }
  }
  if (l15 == 0){
    #pragma unroll
    for (int r = 0; r < 4; ++r){
      int node = nb + g4 * 4 + r;
      u[node] = usum[r];
      v[node] = vsum[r];
    }
  }
}

// ---- layer-2 collapsed aggregation: thread per node via start/cnt ----
__global__ __launch_bounds__(256) void k_pool2(const int* __restrict__ startp, const int* __restrict__ cntp,
                                               const int2* __restrict__ rec,
                                               const float* __restrict__ u, float* __restrict__ sacc){
  int i = blockIdx.x * 256 + threadIdx.x;
  if (i >= TN) return;
  if (i % NPG >= NG) return;     // never read by k_final
  int e0 = startp[i], e1 = e0 + cntp[i];
  float s = 0.f;
  for (int e = e0; e < e1; ++e){
    int2 r = rec[e];
    s += __int_as_float(r.y) * u[r.x & 0x1FFFF];
  }
  sacc[i] = s;
}

// generic block reduction for 1024 threads (16 waves)
__device__ __forceinline__ float blk_red_add16(float x, float* red){
  #pragma unroll
  for (int o = 32; o > 0; o >>= 1) x += __shfl_xor(x, o);
  int wid = threadIdx.x >> 6, lane = threadIdx.x & 63;
  __syncthreads();
  if (lane == 0) red[wid] = x;
  __syncthreads();
  float s = 0.f;
  #pragma unroll
  for (int j = 0; j < 16; ++j) s += red[j];
  return s;
}
__device__ __forceinline__ float blk_red_max16(float x, float* red){
  #pragma unroll
  for (int o = 32; o > 0; o >>= 1) x = fmaxf(x, __shfl_xor(x, o));
  int wid = threadIdx.x >> 6, lane = threadIdx.x & 63;
  __syncthreads();
  if (lane == 0) red[wid] = x;
  __syncthreads();
  float s = red[0];
  #pragma unroll
  for (int j = 1; j < 16; ++j) s = fmaxf(s, red[j]);
  return s;
}

__global__ __launch_bounds__(1024) void k_final(const float* __restrict__ s, const float* __restrict__ vv,
    const float* __restrict__ cbp, const float* __restrict__ gamma, const float* __restrict__ beta,
    float* __restrict__ out){
  __shared__ float t[NG];
  __shared__ float red[16];
  int b = blockIdx.x, tid = threadIdx.x;
  float cb = cbp[0];
  const float inv = 1.f / (float)HD;
  float lsum = 0.f, lsq = 0.f;
  for (int j = tid; j < NG; j += 1024){
    float g = (s[b*NPG + j] + vv[b*NPG + j] + cb) * inv;
    t[j] = g; lsum += g; lsq += g * g;
  }
  float S1 = blk_red_add16(lsum, red);
  float S2 = blk_red_add16(lsq, red);
  float mu = S1 / (float)NG;
  float var = S2 / (float)NG - mu * mu;
  float rstd = rsqrtf(var + 1e-5f);
  float lmax = -3.4e38f;
  for (int j = tid; j < NG; j += 1024){
    float tj = (t[j] - mu) * rstd * gamma[j] + beta[j];
    t[j] = tj; lmax = fmaxf(lmax, tj);
  }
  float M = blk_red_max16(lmax, red);
  float lexp = 0.f;
  for (int j = tid; j < NG; j += 1024) lexp += expf(t[j] - M);
  float S = blk_red_add16(lexp, red);
  float lse = M + logf(S);
  for (int j = tid; j < NG; j += 1024) out[b*NG + j] = t[j] - lse;
}

extern "C" void kernel_launch(void* const* d_in, const int* in_sizes, int n_in,
                              void* d_out, int out_size, void* d_ws, size_t ws_size,
                              hipStream_t stream){
  const float* x      = (const float*)d_in[0];
  const int*   ei     = (const int*)d_in[1];
  const float* ew     = (const float*)d_in[3];
  const float* Wrel1  = (const float*)d_in[4];
  const float* brel1  = (const float*)d_in[5];
  const float* Wroot1 = (const float*)d_in[6];
  const float* Wrel2  = (const float*)d_in[7];
  const float* brel2  = (const float*)d_in[8];
  const float* Wroot2 = (const float*)d_in[9];
  const float* gamma  = (const float*)d_in[10];
  const float* beta   = (const float*)d_in[11];
  const int*   src    = ei;
  const int*   dst    = ei + NE;

  char* ws = (char*)d_ws;
  size_t off_b = 0;
  auto alloc = [&](size_t bytes) -> char* {
    char* p = ws + off_b;
    off_b += (bytes + 511) & ~(size_t)511;
    return p;
  };
  unsigned short* xb    = (unsigned short*)alloc((size_t)TN * HD * 2);
  unsigned short* zb    = (unsigned short*)alloc((size_t)TN * HD * 2);
  unsigned short* W1b   = (unsigned short*)alloc(HD * HD * 2);
  unsigned short* W2b   = (unsigned short*)alloc(HD * HD * 2);
  float*          crel  = (float*)alloc(HD * 4);
  float*          croot = (float*)alloc(HD * 4);
  float*          cbp   = (float*)alloc(4);
  float*          u     = (float*)alloc(TN * 4);
  float*          v     = (float*)alloc(TN * 4);
  float*          sacc  = (float*)alloc(TN * 4);
  int*            startp= (int*)alloc(TN * 4);
  int*            cntp  = (int*)alloc(TN * 4);
  int*            gcur  = (int*)alloc(NBUCK * 4);
  int2*           rec   = (int2*)alloc((size_t)NBUCK * BCAP * 8);

  hipMemsetAsync(gcur, 0, NBUCK * 4, stream);

  k_prepbin<<<PREP_BLK + NCHUNK, 512, 0, stream>>>(x, xb, Wrel1, Wroot1, W1b, W2b,
                                                   Wrel2, Wroot2, brel2, crel, croot, cbp,
                                                   src, dst, ew, gcur, rec);
  k_nsort <<<NBUCK, 512, 0, stream>>>(gcur, rec, startp, cntp);
  k_gather<<<TN/4, 256, 0, stream>>>(startp, cntp, rec, xb, zb);
  k_node  <<<TN/64, 256, 0, stream>>>(zb, xb, W1b, W2b, brel1, crel, croot, u, v);
  k_pool2 <<<(TN+255)/256, 256, 0, stream>>>(startp, cntp, rec, u, sacc);
  k_final <<<NB, 1024, 0, stream>>>(sacc, v, cbp, gamma, beta, (float*)d_out);
}

// Round 12
// 146.041 us; speedup vs baseline: 1.3052x; 1.0356x over previous
//
#include <hip/hip_runtime.h>

#define TN 80000
#define HD 128
#define NE 1280000
#define NB 8
#define NPG 10000
#define NG 8000

#define NBUCK 313           // buckets of 256 nodes (dst>>8)
#define BCAP  4608          // per-bucket record capacity (avg 4090)
#define CHUNK 4096
#define NCHUNK ((NE + CHUNK - 1) / CHUNK)   // 313

#define PX_BLK 2500         // x->bf16: 2500 blocks x 512 thr x 8 elems
#define PW_BLK 32           // weights->bf16: 16384 elems / 512

typedef __attribute__((ext_vector_type(8))) short short8;
typedef __attribute__((ext_vector_type(4))) float f32x4;

__device__ __forceinline__ unsigned short f2bf(float f){
  unsigned int u = __float_as_uint(f);
  u = u + 0x7FFFu + ((u >> 16) & 1u);
  return (unsigned short)(u >> 16);
}

__device__ __forceinline__ short8 pack_bf8(float4 a, float4 b){
  short8 o;
  o[0] = (short)f2bf(a.x); o[1] = (short)f2bf(a.y); o[2] = (short)f2bf(a.z); o[3] = (short)f2bf(a.w);
  o[4] = (short)f2bf(b.x); o[5] = (short)f2bf(b.y); o[6] = (short)f2bf(b.z); o[7] = (short)f2bf(b.w);
  return o;
}

// block 0: colsums ; blocks [1, 1+NCHUNK): chunk-sort edges by bucket (dst>>8)
// record: word0 = src | (dst&255)<<17 ; word1 = weight f32
__global__ __launch_bounds__(512) void k_prepbin(
    const float* __restrict__ Wrel2, const float* __restrict__ Wroot2, const float* __restrict__ brel2,
    float* __restrict__ crel, float* __restrict__ croot, float* __restrict__ cb,
    const int* __restrict__ src, const int* __restrict__ dst, const float* __restrict__ ew,
    int* __restrict__ gcur, int2* __restrict__ rec){
  int b = blockIdx.x;
  int t = threadIdx.x;
  if (b == 0){
    int k = t;
    if (k < HD){
      float a = 0.f, c = 0.f;
      for (int f = 0; f < HD; ++f){ a += Wrel2[f*HD + k]; c += Wroot2[f*HD + k]; }
      crel[k] = a; croot[k] = c;
      if (k == 0){ float s = 0.f; for (int f = 0; f < HD; ++f) s += brel2[f]; cb[0] = s; }
    }
    return;
  }
  // ---- cbin ----
  __shared__ int h[320];
  __shared__ int ex[320];
  __shared__ int2 grec[CHUNK];          // 32 KB
  __shared__ unsigned short gcb[CHUNK]; // 8 KB
  int base = (b - 1) * CHUNK;
  int n = NE - base; if (n > CHUNK) n = CHUNK;

  for (int i = t; i < 320; i += 512) h[i] = 0;
  __syncthreads();

  int pa[8]; float pw[8]; int pc[8];
  #pragma unroll
  for (int k = 0; k < 8; ++k){
    int idx = t + k * 512;
    if (idx < n){
      int e = base + idx;
      int d = dst[e];
      int cbk = d >> 8;
      pa[k] = src[e] | ((d & 255) << 17);
      pw[k] = ew[e];
      pc[k] = cbk;
      atomicAdd(&h[cbk], 1);
    } else pc[k] = -1;
  }
  __syncthreads();

  if (t < 64){
    int b0 = t * 5;
    int s = 0;
    #pragma unroll
    for (int j = 0; j < 5; ++j) s += h[b0 + j];
    int v = s;
    #pragma unroll
    for (int o = 1; o < 64; o <<= 1){ int q = __shfl_up(v, o); if (t >= o) v += q; }
    int run = v - s;
    #pragma unroll
    for (int j = 0; j < 5; ++j){ int q = h[b0 + j]; h[b0 + j] = run; ex[b0 + j] = run; run += q; }
  }
  __syncthreads();

  #pragma unroll
  for (int k = 0; k < 8; ++k){
    if (pc[k] >= 0){
      int p = atomicAdd(&h[pc[k]], 1);
      grec[p] = make_int2(pa[k], __float_as_int(pw[k]));
      gcb[p] = (unsigned short)pc[k];
    }
  }
  __syncthreads();

  for (int i = t; i < NBUCK; i += 512){
    int cnt = h[i] - ex[i];
    int go = 0;
    if (cnt > 0) go = atomicAdd(&gcur[i], cnt);
    ex[i] = i * BCAP + go - ex[i];
  }
  __syncthreads();

  for (int p = t; p < n; p += 512){
    int cbk = gcb[p];
    int ga = ex[cbk] + p;
    if (ga < (cbk + 1) * BCAP) rec[ga] = grec[p];
  }
}

// blocks [0,NBUCK): per-bucket counting sort -> start/cnt (critical path, launched first)
// blocks [NBUCK, NBUCK+PX_BLK): x->bf16 ; then PW_BLK weight-conversion blocks (overlap)
__global__ __launch_bounds__(512) void k_nsconv(const int* __restrict__ gcur, int2* __restrict__ rec,
    int* __restrict__ startp, int* __restrict__ cntp,
    const float* __restrict__ x, unsigned short* __restrict__ xb,
    const float* __restrict__ W1, const float* __restrict__ W2,
    unsigned short* __restrict__ W1b, unsigned short* __restrict__ W2b){
  int b = blockIdx.x, t = threadIdx.x;
  if (b >= NBUCK){
    int cb2 = b - NBUCK;
    if (cb2 < PX_BLK){
      size_t i = ((size_t)cb2 * 512 + t) * 8;
      float4 a0 = *(const float4*)(x + i), a1 = *(const float4*)(x + i + 4);
      *(short8*)(xb + i) = pack_bf8(a0, a1);
    } else {
      int i = (cb2 - PX_BLK) * 512 + t;
      W1b[i] = f2bf(W1[i]);
      W2b[i] = f2bf(W2[i]);
    }
    return;
  }
  // ---- nsort ----
  __shared__ int cnt5[256], ex5[256], cur5[256];
  __shared__ int2 srec[BCAP];          // 36 KB
  int n = gcur[b]; if (n > BCAP) n = BCAP;
  size_t e0 = (size_t)b * BCAP;
  if (t < 256) cnt5[t] = 0;
  __syncthreads();

  int2 rr[9];
  #pragma unroll
  for (int k = 0; k < 9; ++k){
    int i = t + k * 512;
    if (i < n){
      rr[k] = rec[e0 + i];
      atomicAdd(&cnt5[(rr[k].x >> 17) & 255], 1);
    }
  }
  __syncthreads();

  if (t < 64){
    int b0 = t * 4;
    int s = 0;
    #pragma unroll
    for (int j = 0; j < 4; ++j) s += cnt5[b0 + j];
    int v = s;
    #pragma unroll
    for (int o = 1; o < 64; o <<= 1){ int q = __shfl_up(v, o); if (t >= o) v += q; }
    int run = v - s;
    #pragma unroll
    for (int j = 0; j < 4; ++j){ int q = cnt5[b0 + j]; ex5[b0 + j] = run; cur5[b0 + j] = run; run += q; }
  }
  __syncthreads();

  #pragma unroll
  for (int k = 0; k < 9; ++k){
    int i = t + k * 512;
    if (i < n){
      int p = atomicAdd(&cur5[(rr[k].x >> 17) & 255], 1);
      srec[p] = rr[k];
    }
  }
  __syncthreads();

  #pragma unroll
  for (int k = 0; k < 9; ++k){
    int i = t + k * 512;
    if (i < n) rec[e0 + i] = srec[i];
  }
  if (t < 256){
    int node = b * 256 + t;
    if (node < TN){
      startp[node] = (int)e0 + ex5[t];
      cntp[node] = cnt5[t];
    }
  }
}

// ---- layer-1 aggregation: one wave per node, explicit 8-edge dual-load pipeline ----
__global__ __launch_bounds__(256) void k_gather(const int* __restrict__ startp, const int* __restrict__ cntp,
                                                const int2* __restrict__ rec,
                                                const unsigned short* __restrict__ xb, unsigned short* __restrict__ zb){
  int wid = threadIdx.x >> 6, lane = threadIdx.x & 63;
  int node = blockIdx.x * 4 + wid;
  int e0 = startp[node], e1 = e0 + cntp[node];
  int g  = lane >> 4;
  int sl = lane & 15;
  const uint4* xp = (const uint4*)xb;

  float acc[8] = {0,0,0,0,0,0,0,0};

  #define FMA8(P, W)                                                          \
    acc[0] += (W) * __uint_as_float((P).x << 16);                             \
    acc[1] += (W) * __uint_as_float((P).x & 0xFFFF0000u);                     \
    acc[2] += (W) * __uint_as_float((P).y << 16);                             \
    acc[3] += (W) * __uint_as_float((P).y & 0xFFFF0000u);                     \
    acc[4] += (W) * __uint_as_float((P).z << 16);                             \
    acc[5] += (W) * __uint_as_float((P).z & 0xFFFF0000u);                     \
    acc[6] += (W) * __uint_as_float((P).w << 16);                             \
    acc[7] += (W) * __uint_as_float((P).w & 0xFFFF0000u);

  int e = e0;
  for (; e + 8 <= e1; e += 8){
    int2 r0 = rec[e + g];
    int2 r1 = rec[e + 4 + g];
    uint4 p0 = xp[(size_t)(r0.x & 0x1FFFF) * 16 + sl];
    uint4 p1 = xp[(size_t)(r1.x & 0x1FFFF) * 16 + sl];
    float w0 = __int_as_float(r0.y);
    float w1 = __int_as_float(r1.y);
    FMA8(p0, w0)
    FMA8(p1, w1)
  }
  if (e < e1){
    int ee = e + g;
    bool v0 = ee < e1;
    int2 r0 = rec[v0 ? ee : e0];
    int ee1 = e + 4 + g;
    bool v1 = ee1 < e1;
    int2 r1 = rec[v1 ? ee1 : e0];
    uint4 p0 = xp[(size_t)(r0.x & 0x1FFFF) * 16 + sl];
    uint4 p1 = xp[(size_t)(r1.x & 0x1FFFF) * 16 + sl];
    float w0 = v0 ? __int_as_float(r0.y) : 0.f;
    float w1 = v1 ? __int_as_float(r1.y) : 0.f;
    FMA8(p0, w0)
    FMA8(p1, w1)
  }
  #undef FMA8

  #pragma unroll
  for (int o = 16; o <= 32; o <<= 1){
    #pragma unroll
    for (int i = 0; i < 8; ++i) acc[i] += __shfl_xor(acc[i], o);
  }
  if (g == 0){
    uint4 o4;
    o4.x = ((unsigned)f2bf(acc[1]) << 16) | (unsigned)f2bf(acc[0]);
    o4.y = ((unsigned)f2bf(acc[3]) << 16) | (unsigned)f2bf(acc[2]);
    o4.z = ((unsigned)f2bf(acc[5]) << 16) | (unsigned)f2bf(acc[4]);
    o4.w = ((unsigned)f2bf(acc[7]) << 16) | (unsigned)f2bf(acc[6]);
    ((uint4*)zb)[(size_t)node * 16 + sl] = o4;
  }
}

// Fused: h = relu(z@W1^T + x@W2^T + b); u = h . crel; v = h . croot  (bf16 inputs)
__global__ __launch_bounds__(256) void k_node(const unsigned short* __restrict__ zb, const unsigned short* __restrict__ xb,
    const unsigned short* __restrict__ W1b, const unsigned short* __restrict__ W2b,
    const float* __restrict__ brel1, const float* __restrict__ crel, const float* __restrict__ croot,
    float* __restrict__ u, float* __restrict__ v){
  int wid = threadIdx.x >> 6;
  int lane = threadIdx.x & 63;
  int l15 = lane & 15;
  int g4 = lane >> 4;
  int nb = blockIdx.x * 64 + wid * 16;

  const unsigned short* zrow = zb + (size_t)(nb + l15) * HD + g4 * 8;
  const unsigned short* xrow = xb + (size_t)(nb + l15) * HD + g4 * 8;
  short8 az[4], ax[4];
  #pragma unroll
  for (int kk = 0; kk < 4; ++kk){
    az[kk] = *(const short8*)(zrow + kk * 32);
    ax[kk] = *(const short8*)(xrow + kk * 32);
  }

  float usum[4] = {0,0,0,0}, vsum[4] = {0,0,0,0};
  #pragma unroll
  for (int t = 0; t < 8; ++t){
    int kcol = t * 16 + l15;
    const unsigned short* w1r = W1b + (size_t)kcol * HD + g4 * 8;
    const unsigned short* w2r = W2b + (size_t)kcol * HD + g4 * 8;
    f32x4 acc = {0.f, 0.f, 0.f, 0.f};
    #pragma unroll
    for (int kk = 0; kk < 4; ++kk)
      acc = __builtin_amdgcn_mfma_f32_16x16x32_bf16(az[kk], *(const short8*)(w1r + kk * 32), acc, 0, 0, 0);
    #pragma unroll
    for (int kk = 0; kk < 4; ++kk)
      acc = __builtin_amdgcn_mfma_f32_16x16x32_bf16(ax[kk], *(const short8*)(w2r + kk * 32), acc, 0, 0, 0);
    float bias = brel1[kcol], cr = crel[kcol], co = croot[kcol];
    #pragma unroll
    for (int r = 0; r < 4; ++r){
      float h = fmaxf(acc[r] + bias, 0.f);
      usum[r] += h * cr;
      vsum[r] += h * co;
    }
  }
  #pragma unroll
  for (int o = 1; o < 16; o <<= 1){
    #pragma unroll
    for (int r = 0; r < 4; ++r){
      usum[r] += __shfl_xor(usum[r], o);
      vsum[r] += __shfl_xor(vsum[r], o);
    }
  }
  if (l15 == 0){
    #pragma unroll
    for (int r = 0; r < 4; ++r){
      int node = nb + g4 * 4 + r;
      u[node] = usum[r];
      v[node] = vsum[r];
    }
  }
}

// ---- layer-2 collapsed aggregation: thread per node, dual-load unroll ----
__global__ __launch_bounds__(256) void k_pool2(const int* __restrict__ startp, const int* __restrict__ cntp,
                                               const int2* __restrict__ rec,
                                               const float* __restrict__ u, float* __restrict__ sacc){
  int i = blockIdx.x * 256 + threadIdx.x;
  if (i >= TN) return;
  if (i % NPG >= NG) return;     // never read by k_final
  int e0 = startp[i], e1 = e0 + cntp[i];
  float s = 0.f;
  int e = e0;
  for (; e + 2 <= e1; e += 2){
    int2 r0 = rec[e];
    int2 r1 = rec[e + 1];
    float u0 = u[r0.x & 0x1FFFF];
    float u1 = u[r1.x & 0x1FFFF];
    s += __int_as_float(r0.y) * u0 + __int_as_float(r1.y) * u1;
  }
  if (e < e1){
    int2 r = rec[e];
    s += __int_as_float(r.y) * u[r.x & 0x1FFFF];
  }
  sacc[i] = s;
}

// generic block reduction for 1024 threads (16 waves)
__device__ __forceinline__ float blk_red_add16(float x, float* red){
  #pragma unroll
  for (int o = 32; o > 0; o >>= 1) x += __shfl_xor(x, o);
  int wid = threadIdx.x >> 6, lane = threadIdx.x & 63;
  __syncthreads();
  if (lane == 0) red[wid] = x;
  __syncthreads();
  float s = 0.f;
  #pragma unroll
  for (int j = 0; j < 16; ++j) s += red[j];
  return s;
}
__device__ __forceinline__ float blk_red_max16(float x, float* red){
  #pragma unroll
  for (int o = 32; o > 0; o >>= 1) x = fmaxf(x, __shfl_xor(x, o));
  int wid = threadIdx.x >> 6, lane = threadIdx.x & 63;
  __syncthreads();
  if (lane == 0) red[wid] = x;
  __syncthreads();
  float s = red[0];
  #pragma unroll
  for (int j = 1; j < 16; ++j) s = fmaxf(s, red[j]);
  return s;
}

__global__ __launch_bounds__(1024) void k_final(const float* __restrict__ s, const float* __restrict__ vv,
    const float* __restrict__ cbp, const float* __restrict__ gamma, const float* __restrict__ beta,
    float* __restrict__ out){
  __shared__ float t[NG];
  __shared__ float red[16];
  int b = blockIdx.x, tid = threadIdx.x;
  float cb = cbp[0];
  const float inv = 1.f / (float)HD;
  float lsum = 0.f, lsq = 0.f;
  for (int j = tid; j < NG; j += 1024){
    float g = (s[b*NPG + j] + vv[b*NPG + j] + cb) * inv;
    t[j] = g; lsum += g; lsq += g * g;
  }
  float S1 = blk_red_add16(lsum, red);
  float S2 = blk_red_add16(lsq, red);
  float mu = S1 / (float)NG;
  float var = S2 / (float)NG - mu * mu;
  float rstd = rsqrtf(var + 1e-5f);
  float lmax = -3.4e38f;
  for (int j = tid; j < NG; j += 1024){
    float tj = (t[j] - mu) * rstd * gamma[j] + beta[j];
    t[j] = tj; lmax = fmaxf(lmax, tj);
  }
  float M = blk_red_max16(lmax, red);
  float lexp = 0.f;
  for (int j = tid; j < NG; j += 1024) lexp += expf(t[j] - M);
  float S = blk_red_add16(lexp, red);
  float lse = M + logf(S);
  for (int j = tid; j < NG; j += 1024) out[b*NG + j] = t[j] - lse;
}

extern "C" void kernel_launch(void* const* d_in, const int* in_sizes, int n_in,
                              void* d_out, int out_size, void* d_ws, size_t ws_size,
                              hipStream_t stream){
  const float* x      = (const float*)d_in[0];
  const int*   ei     = (const int*)d_in[1];
  const float* ew     = (const float*)d_in[3];
  const float* Wrel1  = (const float*)d_in[4];
  const float* brel1  = (const float*)d_in[5];
  const float* Wroot1 = (const float*)d_in[6];
  const float* Wrel2  = (const float*)d_in[7];
  const float* brel2  = (const float*)d_in[8];
  const float* Wroot2 = (const float*)d_in[9];
  const float* gamma  = (const float*)d_in[10];
  const float* beta   = (const float*)d_in[11];
  const int*   src    = ei;
  const int*   dst    = ei + NE;

  char* ws = (char*)d_ws;
  size_t off_b = 0;
  auto alloc = [&](size_t bytes) -> char* {
    char* p = ws + off_b;
    off_b += (bytes + 511) & ~(size_t)511;
    return p;
  };
  unsigned short* xb    = (unsigned short*)alloc((size_t)TN * HD * 2);
  unsigned short* zb    = (unsigned short*)alloc((size_t)TN * HD * 2);
  unsigned short* W1b   = (unsigned short*)alloc(HD * HD * 2);
  unsigned short* W2b   = (unsigned short*)alloc(HD * HD * 2);
  float*          crel  = (float*)alloc(HD * 4);
  float*          croot = (float*)alloc(HD * 4);
  float*          cbp   = (float*)alloc(4);
  float*          u     = (float*)alloc(TN * 4);
  float*          v     = (float*)alloc(TN * 4);
  float*          sacc  = (float*)alloc(TN * 4);
  int*            startp= (int*)alloc(TN * 4);
  int*            cntp  = (int*)alloc(TN * 4);
  int*            gcur  = (int*)alloc(NBUCK * 4);
  int2*           rec   = (int2*)alloc((size_t)NBUCK * BCAP * 8);

  hipMemsetAsync(gcur, 0, NBUCK * 4, stream);

  k_prepbin<<<1 + NCHUNK, 512, 0, stream>>>(Wrel2, Wroot2, brel2, crel, croot, cbp,
                                            src, dst, ew, gcur, rec);
  k_nsconv<<<NBUCK + PX_BLK + PW_BLK, 512, 0, stream>>>(gcur, rec, startp, cntp,
                                                        x, xb, Wrel1, Wroot1, W1b, W2b);
  k_gather<<<TN/4, 256, 0, stream>>>(startp, cntp, rec, xb, zb);
  k_node  <<<TN/64, 256, 0, stream>>>(zb, xb, W1b, W2b, brel1, crel, croot, u, v);
  k_pool2 <<<(TN+255)/256, 256, 0, stream>>>(startp, cntp, rec, u, sacc);
  k_final <<<NB, 1024, 0, stream>>>(sacc, v, cbp, gamma, beta, (float*)d_out);
}

// Round 13
// 138.676 us; speedup vs baseline: 1.3745x; 1.0531x over previous
//
#include <hip/hip_runtime.h>

#define TN 80000
#define HD 128
#define NE 1280000
#define NB 8
#define NPG 10000
#define NG 8000

#define NBUCK 625           // buckets of 128 nodes (dst>>7)
#define BCAP  2304          // per-bucket record capacity (avg 2048, +5.7 sigma)
#define CHUNK 4096
#define NCHUNK ((NE + CHUNK - 1) / CHUNK)   // 313

#define PX_BLK 2500         // x->bf16: 2500 blocks x 512 thr x 8 elems
#define PW_BLK 32           // weights->bf16: 16384 elems / 512

typedef __attribute__((ext_vector_type(8))) short short8;
typedef __attribute__((ext_vector_type(4))) float f32x4;

__device__ __forceinline__ unsigned short f2bf(float f){
  unsigned int u = __float_as_uint(f);
  u = u + 0x7FFFu + ((u >> 16) & 1u);
  return (unsigned short)(u >> 16);
}

__device__ __forceinline__ short8 pack_bf8(float4 a, float4 b){
  short8 o;
  o[0] = (short)f2bf(a.x); o[1] = (short)f2bf(a.y); o[2] = (short)f2bf(a.z); o[3] = (short)f2bf(a.w);
  o[4] = (short)f2bf(b.x); o[5] = (short)f2bf(b.y); o[6] = (short)f2bf(b.z); o[7] = (short)f2bf(b.w);
  return o;
}

// block 0: colsums ; blocks [1, 1+NCHUNK): chunk-sort edges by bucket (dst>>7)
// record: word0 = src | (dst&127)<<17 ; word1 = weight f32
__global__ __launch_bounds__(512) void k_prepbin(
    const float* __restrict__ Wrel2, const float* __restrict__ Wroot2, const float* __restrict__ brel2,
    float* __restrict__ crel, float* __restrict__ croot, float* __restrict__ cb,
    const int* __restrict__ src, const int* __restrict__ dst, const float* __restrict__ ew,
    int* __restrict__ gcur, int2* __restrict__ rec){
  int b = blockIdx.x;
  int t = threadIdx.x;
  if (b == 0){
    int k = t;
    if (k < HD){
      float a = 0.f, c = 0.f;
      for (int f = 0; f < HD; ++f){ a += Wrel2[f*HD + k]; c += Wroot2[f*HD + k]; }
      crel[k] = a; croot[k] = c;
      if (k == 0){ float s = 0.f; for (int f = 0; f < HD; ++f) s += brel2[f]; cb[0] = s; }
    }
    return;
  }
  // ---- cbin ----
  __shared__ int h[640];
  __shared__ int ex[640];
  __shared__ int2 grec[CHUNK];          // 32 KB
  __shared__ unsigned short gcb[CHUNK]; // 8 KB
  int base = (b - 1) * CHUNK;
  int n = NE - base; if (n > CHUNK) n = CHUNK;

  for (int i = t; i < 640; i += 512) h[i] = 0;
  __syncthreads();

  int pa[8]; float pw[8]; int pc[8];
  #pragma unroll
  for (int k = 0; k < 8; ++k){
    int idx = t + k * 512;
    if (idx < n){
      int e = base + idx;
      int d = dst[e];
      int cbk = d >> 7;
      pa[k] = src[e] | ((d & 127) << 17);
      pw[k] = ew[e];
      pc[k] = cbk;
      atomicAdd(&h[cbk], 1);
    } else pc[k] = -1;
  }
  __syncthreads();

  // exclusive scan of 640 counters by wave 0 (10 slots/lane + shfl scan)
  if (t < 64){
    int b0 = t * 10;
    int s = 0;
    #pragma unroll
    for (int j = 0; j < 10; ++j) s += h[b0 + j];
    int v = s;
    #pragma unroll
    for (int o = 1; o < 64; o <<= 1){ int q = __shfl_up(v, o); if (t >= o) v += q; }
    int run = v - s;
    #pragma unroll
    for (int j = 0; j < 10; ++j){ int q = h[b0 + j]; h[b0 + j] = run; ex[b0 + j] = run; run += q; }
  }
  __syncthreads();

  #pragma unroll
  for (int k = 0; k < 8; ++k){
    if (pc[k] >= 0){
      int p = atomicAdd(&h[pc[k]], 1);
      grec[p] = make_int2(pa[k], __float_as_int(pw[k]));
      gcb[p] = (unsigned short)pc[k];
    }
  }
  __syncthreads();

  for (int i = t; i < NBUCK; i += 512){
    int cnt = h[i] - ex[i];
    int go = 0;
    if (cnt > 0) go = atomicAdd(&gcur[i], cnt);
    ex[i] = i * BCAP + go - ex[i];
  }
  __syncthreads();

  for (int p = t; p < n; p += 512){
    int cbk = gcb[p];
    int ga = ex[cbk] + p;
    if (ga < (cbk + 1) * BCAP) rec[ga] = grec[p];
  }
}

// blocks [0,NBUCK): per-bucket counting sort -> start/cnt (critical path, launched first)
// blocks [NBUCK, ...): x->bf16 then weight conversion (overlap work)
__global__ __launch_bounds__(512) void k_nsconv(const int* __restrict__ gcur, int2* __restrict__ rec,
    int* __restrict__ startp, int* __restrict__ cntp,
    const float* __restrict__ x, unsigned short* __restrict__ xb,
    const float* __restrict__ W1, const float* __restrict__ W2,
    unsigned short* __restrict__ W1b, unsigned short* __restrict__ W2b){
  int b = blockIdx.x, t = threadIdx.x;
  if (b >= NBUCK){
    int cb2 = b - NBUCK;
    if (cb2 < PX_BLK){
      size_t i = ((size_t)cb2 * 512 + t) * 8;
      float4 a0 = *(const float4*)(x + i), a1 = *(const float4*)(x + i + 4);
      *(short8*)(xb + i) = pack_bf8(a0, a1);
    } else {
      int i = (cb2 - PX_BLK) * 512 + t;
      W1b[i] = f2bf(W1[i]);
      W2b[i] = f2bf(W2[i]);
    }
    return;
  }
  // ---- nsort: counting sort of <=BCAP records by node (7-bit local id) ----
  __shared__ int cnt5[128], ex5[128], cur5[128];
  __shared__ int2 srec[BCAP];          // ~18.4 KB
  int n = gcur[b]; if (n > BCAP) n = BCAP;
  size_t e0 = (size_t)b * BCAP;
  if (t < 128) cnt5[t] = 0;
  __syncthreads();

  int2 rr[5];                           // ceil(BCAP/512) == 5
  #pragma unroll
  for (int k = 0; k < 5; ++k){
    int i = t + k * 512;
    if (i < n){
      rr[k] = rec[e0 + i];
      atomicAdd(&cnt5[(rr[k].x >> 17) & 127], 1);
    }
  }
  __syncthreads();

  if (t < 64){
    int b0 = t * 2;
    int s = cnt5[b0] + cnt5[b0 + 1];
    int v = s;
    #pragma unroll
    for (int o = 1; o < 64; o <<= 1){ int q = __shfl_up(v, o); if (t >= o) v += q; }
    int run = v - s;
    int q0 = cnt5[b0];
    ex5[b0] = run; cur5[b0] = run;
    ex5[b0 + 1] = run + q0; cur5[b0 + 1] = run + q0;
  }
  __syncthreads();

  #pragma unroll
  for (int k = 0; k < 5; ++k){
    int i = t + k * 512;
    if (i < n){
      int p = atomicAdd(&cur5[(rr[k].x >> 17) & 127], 1);
      srec[p] = rr[k];
    }
  }
  __syncthreads();

  #pragma unroll
  for (int k = 0; k < 5; ++k){
    int i = t + k * 512;
    if (i < n) rec[e0 + i] = srec[i];
  }
  if (t < 128){
    int node = b * 128 + t;
    if (node < TN){
      startp[node] = (int)e0 + ex5[t];
      cntp[node] = cnt5[t];
    }
  }
}

// ---- layer-1 aggregation: one wave per node, explicit 8-edge dual-load pipeline ----
__global__ __launch_bounds__(256) void k_gather(const int* __restrict__ startp, const int* __restrict__ cntp,
                                                const int2* __restrict__ rec,
                                                const unsigned short* __restrict__ xb, unsigned short* __restrict__ zb){
  int wid = threadIdx.x >> 6, lane = threadIdx.x & 63;
  int node = blockIdx.x * 4 + wid;
  int e0 = startp[node], e1 = e0 + cntp[node];
  int g  = lane >> 4;
  int sl = lane & 15;
  const uint4* xp = (const uint4*)xb;

  float acc[8] = {0,0,0,0,0,0,0,0};

  #define FMA8(P, W)                                                          \
    acc[0] += (W) * __uint_as_float((P).x << 16);                             \
    acc[1] += (W) * __uint_as_float((P).x & 0xFFFF0000u);                     \
    acc[2] += (W) * __uint_as_float((P).y << 16);                             \
    acc[3] += (W) * __uint_as_float((P).y & 0xFFFF0000u);                     \
    acc[4] += (W) * __uint_as_float((P).z << 16);                             \
    acc[5] += (W) * __uint_as_float((P).z & 0xFFFF0000u);                     \
    acc[6] += (W) * __uint_as_float((P).w << 16);                             \
    acc[7] += (W) * __uint_as_float((P).w & 0xFFFF0000u);

  int e = e0;
  for (; e + 8 <= e1; e += 8){
    int2 r0 = rec[e + g];
    int2 r1 = rec[e + 4 + g];
    uint4 p0 = xp[(size_t)(r0.x & 0x1FFFF) * 16 + sl];
    uint4 p1 = xp[(size_t)(r1.x & 0x1FFFF) * 16 + sl];
    float w0 = __int_as_float(r0.y);
    float w1 = __int_as_float(r1.y);
    FMA8(p0, w0)
    FMA8(p1, w1)
  }
  if (e < e1){
    int ee = e + g;
    bool v0 = ee < e1;
    int2 r0 = rec[v0 ? ee : e0];
    int ee1 = e + 4 + g;
    bool v1 = ee1 < e1;
    int2 r1 = rec[v1 ? ee1 : e0];
    uint4 p0 = xp[(size_t)(r0.x & 0x1FFFF) * 16 + sl];
    uint4 p1 = xp[(size_t)(r1.x & 0x1FFFF) * 16 + sl];
    float w0 = v0 ? __int_as_float(r0.y) : 0.f;
    float w1 = v1 ? __int_as_float(r1.y) : 0.f;
    FMA8(p0, w0)
    FMA8(p1, w1)
  }
  #undef FMA8

  #pragma unroll
  for (int o = 16; o <= 32; o <<= 1){
    #pragma unroll
    for (int i = 0; i < 8; ++i) acc[i] += __shfl_xor(acc[i], o);
  }
  if (g == 0){
    uint4 o4;
    o4.x = ((unsigned)f2bf(acc[1]) << 16) | (unsigned)f2bf(acc[0]);
    o4.y = ((unsigned)f2bf(acc[3]) << 16) | (unsigned)f2bf(acc[2]);
    o4.z = ((unsigned)f2bf(acc[5]) << 16) | (unsigned)f2bf(acc[4]);
    o4.w = ((unsigned)f2bf(acc[7]) << 16) | (unsigned)f2bf(acc[6]);
    ((uint4*)zb)[(size_t)node * 16 + sl] = o4;
  }
}

// Fused: h = relu(z@W1^T + x@W2^T + b); u = h.crel; v = h.croot
// wave handles 32 nodes (2 tiles); weight fragments reused across both tiles
__global__ __launch_bounds__(256) void k_node(const unsigned short* __restrict__ zb, const unsigned short* __restrict__ xb,
    const unsigned short* __restrict__ W1b, const unsigned short* __restrict__ W2b,
    const float* __restrict__ brel1, const float* __restrict__ crel, const float* __restrict__ croot,
    float* __restrict__ u, float* __restrict__ v){
  int wid = threadIdx.x >> 6;
  int lane = threadIdx.x & 63;
  int l15 = lane & 15;
  int g4 = lane >> 4;
  int nb = blockIdx.x * 128 + wid * 32;

  short8 az[2][4], ax[2][4];
  #pragma unroll
  for (int nt = 0; nt < 2; ++nt){
    const unsigned short* zrow = zb + (size_t)(nb + nt * 16 + l15) * HD + g4 * 8;
    const unsigned short* xrow = xb + (size_t)(nb + nt * 16 + l15) * HD + g4 * 8;
    #pragma unroll
    for (int kk = 0; kk < 4; ++kk){
      az[nt][kk] = *(const short8*)(zrow + kk * 32);
      ax[nt][kk] = *(const short8*)(xrow + kk * 32);
    }
  }

  float usum[2][4] = {{0,0,0,0},{0,0,0,0}}, vsum[2][4] = {{0,0,0,0},{0,0,0,0}};
  #pragma unroll
  for (int t = 0; t < 8; ++t){
    int kcol = t * 16 + l15;
    const unsigned short* w1r = W1b + (size_t)kcol * HD + g4 * 8;
    const unsigned short* w2r = W2b + (size_t)kcol * HD + g4 * 8;
    short8 w1f[4], w2f[4];
    #pragma unroll
    for (int kk = 0; kk < 4; ++kk){
      w1f[kk] = *(const short8*)(w1r + kk * 32);
      w2f[kk] = *(const short8*)(w2r + kk * 32);
    }
    float bias = brel1[kcol], cr = crel[kcol], co = croot[kcol];
    #pragma unroll
    for (int nt = 0; nt < 2; ++nt){
      f32x4 acc = {0.f, 0.f, 0.f, 0.f};
      #pragma unroll
      for (int kk = 0; kk < 4; ++kk)
        acc = __builtin_amdgcn_mfma_f32_16x16x32_bf16(az[nt][kk], w1f[kk], acc, 0, 0, 0);
      #pragma unroll
      for (int kk = 0; kk < 4; ++kk)
        acc = __builtin_amdgcn_mfma_f32_16x16x32_bf16(ax[nt][kk], w2f[kk], acc, 0, 0, 0);
      #pragma unroll
      for (int r = 0; r < 4; ++r){
        float h = fmaxf(acc[r] + bias, 0.f);
        usum[nt][r] += h * cr;
        vsum[nt][r] += h * co;
      }
    }
  }
  #pragma unroll
  for (int o = 1; o < 16; o <<= 1){
    #pragma unroll
    for (int nt = 0; nt < 2; ++nt){
      #pragma unroll
      for (int r = 0; r < 4; ++r){
        usum[nt][r] += __shfl_xor(usum[nt][r], o);
        vsum[nt][r] += __shfl_xor(vsum[nt][r], o);
      }
    }
  }
  if (l15 == 0){
    #pragma unroll
    for (int nt = 0; nt < 2; ++nt){
      #pragma unroll
      for (int r = 0; r < 4; ++r){
        int node = nb + nt * 16 + g4 * 4 + r;
        u[node] = usum[nt][r];
        v[node] = vsum[nt][r];
      }
    }
  }
}

// ---- layer-2 collapsed aggregation: thread per node, dual-load unroll ----
__global__ __launch_bounds__(256) void k_pool2(const int* __restrict__ startp, const int* __restrict__ cntp,
                                               const int2* __restrict__ rec,
                                               const float* __restrict__ u, float* __restrict__ sacc){
  int i = blockIdx.x * 256 + threadIdx.x;
  if (i >= TN) return;
  if (i % NPG >= NG) return;     // never read by k_final
  int e0 = startp[i], e1 = e0 + cntp[i];
  float s = 0.f;
  int e = e0;
  for (; e + 2 <= e1; e += 2){
    int2 r0 = rec[e];
    int2 r1 = rec[e + 1];
    float u0 = u[r0.x & 0x1FFFF];
    float u1 = u[r1.x & 0x1FFFF];
    s += __int_as_float(r0.y) * u0 + __int_as_float(r1.y) * u1;
  }
  if (e < e1){
    int2 r = rec[e];
    s += __int_as_float(r.y) * u[r.x & 0x1FFFF];
  }
  sacc[i] = s;
}

// generic block reduction for 1024 threads (16 waves)
__device__ __forceinline__ float blk_red_add16(float x, float* red){
  #pragma unroll
  for (int o = 32; o > 0; o >>= 1) x += __shfl_xor(x, o);
  int wid = threadIdx.x >> 6, lane = threadIdx.x & 63;
  __syncthreads();
  if (lane == 0) red[wid] = x;
  __syncthreads();
  float s = 0.f;
  #pragma unroll
  for (int j = 0; j < 16; ++j) s += red[j];
  return s;
}
__device__ __forceinline__ float blk_red_max16(float x, float* red){
  #pragma unroll
  for (int o = 32; o > 0; o >>= 1) x = fmaxf(x, __shfl_xor(x, o));
  int wid = threadIdx.x >> 6, lane = threadIdx.x & 63;
  __syncthreads();
  if (lane == 0) red[wid] = x;
  __syncthreads();
  float s = red[0];
  #pragma unroll
  for (int j = 1; j < 16; ++j) s = fmaxf(s, red[j]);
  return s;
}

__global__ __launch_bounds__(1024) void k_final(const float* __restrict__ s, const float* __restrict__ vv,
    const float* __restrict__ cbp, const float* __restrict__ gamma, const float* __restrict__ beta,
    float* __restrict__ out){
  __shared__ float t[NG];
  __shared__ float red[16];
  int b = blockIdx.x, tid = threadIdx.x;
  float cb = cbp[0];
  const float inv = 1.f / (float)HD;
  float lsum = 0.f, lsq = 0.f;
  for (int j = tid; j < NG; j += 1024){
    float g = (s[b*NPG + j] + vv[b*NPG + j] + cb) * inv;
    t[j] = g; lsum += g; lsq += g * g;
  }
  float S1 = blk_red_add16(lsum, red);
  float S2 = blk_red_add16(lsq, red);
  float mu = S1 / (float)NG;
  float var = S2 / (float)NG - mu * mu;
  float rstd = rsqrtf(var + 1e-5f);
  float lmax = -3.4e38f;
  for (int j = tid; j < NG; j += 1024){
    float tj = (t[j] - mu) * rstd * gamma[j] + beta[j];
    t[j] = tj; lmax = fmaxf(lmax, tj);
  }
  float M = blk_red_max16(lmax, red);
  float lexp = 0.f;
  for (int j = tid; j < NG; j += 1024) lexp += expf(t[j] - M);
  float S = blk_red_add16(lexp, red);
  float lse = M + logf(S);
  for (int j = tid; j < NG; j += 1024) out[b*NG + j] = t[j] - lse;
}

extern "C" void kernel_launch(void* const* d_in, const int* in_sizes, int n_in,
                              void* d_out, int out_size, void* d_ws, size_t ws_size,
                              hipStream_t stream){
  const float* x      = (const float*)d_in[0];
  const int*   ei     = (const int*)d_in[1];
  const float* ew     = (const float*)d_in[3];
  const float* Wrel1  = (const float*)d_in[4];
  const float* brel1  = (const float*)d_in[5];
  const float* Wroot1 = (const float*)d_in[6];
  const float* Wrel2  = (const float*)d_in[7];
  const float* brel2  = (const float*)d_in[8];
  const float* Wroot2 = (const float*)d_in[9];
  const float* gamma  = (const float*)d_in[10];
  const float* beta   = (const float*)d_in[11];
  const int*   src    = ei;
  const int*   dst    = ei + NE;

  char* ws = (char*)d_ws;
  size_t off_b = 0;
  auto alloc = [&](size_t bytes) -> char* {
    char* p = ws + off_b;
    off_b += (bytes + 511) & ~(size_t)511;
    return p;
  };
  unsigned short* xb    = (unsigned short*)alloc((size_t)TN * HD * 2);
  unsigned short* zb    = (unsigned short*)alloc((size_t)TN * HD * 2);
  unsigned short* W1b   = (unsigned short*)alloc(HD * HD * 2);
  unsigned short* W2b   = (unsigned short*)alloc(HD * HD * 2);
  float*          crel  = (float*)alloc(HD * 4);
  float*          croot = (float*)alloc(HD * 4);
  float*          cbp   = (float*)alloc(4);
  float*          u     = (float*)alloc(TN * 4);
  float*          v     = (float*)alloc(TN * 4);
  float*          sacc  = (float*)alloc(TN * 4);
  int*            startp= (int*)alloc(TN * 4);
  int*            cntp  = (int*)alloc(TN * 4);
  int*            gcur  = (int*)alloc(NBUCK * 4);
  int2*           rec   = (int2*)alloc((size_t)NBUCK * BCAP * 8);

  hipMemsetAsync(gcur, 0, NBUCK * 4, stream);

  k_prepbin<<<1 + NCHUNK, 512, 0, stream>>>(Wrel2, Wroot2, brel2, crel, croot, cbp,
                                            src, dst, ew, gcur, rec);
  k_nsconv<<<NBUCK + PX_BLK + PW_BLK, 512, 0, stream>>>(gcur, rec, startp, cntp,
                                                        x, xb, Wrel1, Wroot1, W1b, W2b);
  k_gather<<<TN/4, 256, 0, stream>>>(startp, cntp, rec, xb, zb);
  k_node  <<<TN/128, 256, 0, stream>>>(zb, xb, W1b, W2b, brel1, crel, croot, u, v);
  k_pool2 <<<(TN+255)/256, 256, 0, stream>>>(startp, cntp, rec, u, sacc);
  k_final <<<NB, 1024, 0, stream>>>(sacc, v, cbp, gamma, beta, (float*)d_out);
}

// Round 14
// 135.626 us; speedup vs baseline: 1.4054x; 1.0225x over previous
//
#include <hip/hip_runtime.h>

#define TN 80000
#define HD 128
#define NE 1280000
#define NB 8
#define NPG 10000
#define NG 8000

#define NBUCK 625           // buckets of 128 nodes (dst>>7)
#define BCAP  2304          // per-bucket record capacity (avg 2048)
#define CHUNK 4096
#define NCHUNK ((NE + CHUNK - 1) / CHUNK)   // 313

#define PX_BLK 2500         // x->bf16: 2500 blocks x 512 thr x 8 elems
#define PW_BLK 32           // weights->bf16: 16384 elems / 512

typedef __attribute__((ext_vector_type(8))) short short8;
typedef __attribute__((ext_vector_type(4))) float f32x4;

__device__ __forceinline__ unsigned short f2bf(float f){
  unsigned int u = __float_as_uint(f);
  u = u + 0x7FFFu + ((u >> 16) & 1u);
  return (unsigned short)(u >> 16);
}

__device__ __forceinline__ short8 pack_bf8(float4 a, float4 b){
  short8 o;
  o[0] = (short)f2bf(a.x); o[1] = (short)f2bf(a.y); o[2] = (short)f2bf(a.z); o[3] = (short)f2bf(a.w);
  o[4] = (short)f2bf(b.x); o[5] = (short)f2bf(b.y); o[6] = (short)f2bf(b.z); o[7] = (short)f2bf(b.w);
  return o;
}

// blocks [0,NCHUNK): chunk-sort edges by bucket (dst>>7) ; NCHUNK: colsums ;
// rest: x->bf16 and W->bf16 conversions (independent work, overlaps cbin)
// record: word0 = src | (dst&127)<<17 ; word1 = weight f32
__global__ __launch_bounds__(512) void k_prepbin(
    const float* __restrict__ Wrel2, const float* __restrict__ Wroot2, const float* __restrict__ brel2,
    float* __restrict__ crel, float* __restrict__ croot, float* __restrict__ cb,
    const int* __restrict__ src, const int* __restrict__ dst, const float* __restrict__ ew,
    int* __restrict__ gcur, int2* __restrict__ rec,
    const float* __restrict__ x, unsigned short* __restrict__ xb,
    const float* __restrict__ W1, const float* __restrict__ W2,
    unsigned short* __restrict__ W1b, unsigned short* __restrict__ W2b){
  int b = blockIdx.x;
  int t = threadIdx.x;
  if (b >= NCHUNK){
    if (b == NCHUNK){
      int k = t;
      if (k < HD){
        float a = 0.f, c = 0.f;
        for (int f = 0; f < HD; ++f){ a += Wrel2[f*HD + k]; c += Wroot2[f*HD + k]; }
        crel[k] = a; croot[k] = c;
        if (k == 0){ float s = 0.f; for (int f = 0; f < HD; ++f) s += brel2[f]; cb[0] = s; }
      }
      return;
    }
    int cb2 = b - NCHUNK - 1;
    if (cb2 < PX_BLK){
      size_t i = ((size_t)cb2 * 512 + t) * 8;
      float4 a0 = *(const float4*)(x + i), a1 = *(const float4*)(x + i + 4);
      *(short8*)(xb + i) = pack_bf8(a0, a1);
    } else {
      int i = (cb2 - PX_BLK) * 512 + t;
      W1b[i] = f2bf(W1[i]);
      W2b[i] = f2bf(W2[i]);
    }
    return;
  }
  // ---- cbin ----
  __shared__ int h[640];
  __shared__ int ex[640];
  __shared__ int2 grec[CHUNK];          // 32 KB
  __shared__ unsigned short gcb[CHUNK]; // 8 KB
  int base = b * CHUNK;
  int n = NE - base; if (n > CHUNK) n = CHUNK;

  for (int i = t; i < 640; i += 512) h[i] = 0;
  __syncthreads();

  int pa[8]; float pw[8]; int pc[8];
  #pragma unroll
  for (int k = 0; k < 8; ++k){
    int idx = t + k * 512;
    if (idx < n){
      int e = base + idx;
      int d = dst[e];
      int cbk = d >> 7;
      pa[k] = src[e] | ((d & 127) << 17);
      pw[k] = ew[e];
      pc[k] = cbk;
      atomicAdd(&h[cbk], 1);
    } else pc[k] = -1;
  }
  __syncthreads();

  if (t < 64){
    int b0 = t * 10;
    int s = 0;
    #pragma unroll
    for (int j = 0; j < 10; ++j) s += h[b0 + j];
    int v = s;
    #pragma unroll
    for (int o = 1; o < 64; o <<= 1){ int q = __shfl_up(v, o); if (t >= o) v += q; }
    int run = v - s;
    #pragma unroll
    for (int j = 0; j < 10; ++j){ int q = h[b0 + j]; h[b0 + j] = run; ex[b0 + j] = run; run += q; }
  }
  __syncthreads();

  #pragma unroll
  for (int k = 0; k < 8; ++k){
    if (pc[k] >= 0){
      int p = atomicAdd(&h[pc[k]], 1);
      grec[p] = make_int2(pa[k], __float_as_int(pw[k]));
      gcb[p] = (unsigned short)pc[k];
    }
  }
  __syncthreads();

  for (int i = t; i < NBUCK; i += 512){
    int cnt = h[i] - ex[i];
    int go = 0;
    if (cnt > 0) go = atomicAdd(&gcur[i], cnt);
    ex[i] = i * BCAP + go - ex[i];
  }
  __syncthreads();

  for (int p = t; p < n; p += 512){
    int cbk = gcb[p];
    int ga = ex[cbk] + p;
    if (ga < (cbk + 1) * BCAP) rec[ga] = grec[p];
  }
}

// pure nsort: per-bucket counting sort by node (7-bit local id) -> start/cnt
__global__ __launch_bounds__(512) void k_nsort(const int* __restrict__ gcur, int2* __restrict__ rec,
                                               int* __restrict__ startp, int* __restrict__ cntp){
  __shared__ int cnt5[128], ex5[128], cur5[128];
  __shared__ int2 srec[BCAP];          // ~18.4 KB
  int t = threadIdx.x, b = blockIdx.x;
  int n = gcur[b]; if (n > BCAP) n = BCAP;
  size_t e0 = (size_t)b * BCAP;
  if (t < 128) cnt5[t] = 0;
  __syncthreads();

  int2 rr[5];
  #pragma unroll
  for (int k = 0; k < 5; ++k){
    int i = t + k * 512;
    if (i < n){
      rr[k] = rec[e0 + i];
      atomicAdd(&cnt5[(rr[k].x >> 17) & 127], 1);
    }
  }
  __syncthreads();

  if (t < 64){
    int b0 = t * 2;
    int s = cnt5[b0] + cnt5[b0 + 1];
    int v = s;
    #pragma unroll
    for (int o = 1; o < 64; o <<= 1){ int q = __shfl_up(v, o); if (t >= o) v += q; }
    int run = v - s;
    int q0 = cnt5[b0];
    ex5[b0] = run; cur5[b0] = run;
    ex5[b0 + 1] = run + q0; cur5[b0 + 1] = run + q0;
  }
  __syncthreads();

  #pragma unroll
  for (int k = 0; k < 5; ++k){
    int i = t + k * 512;
    if (i < n){
      int p = atomicAdd(&cur5[(rr[k].x >> 17) & 127], 1);
      srec[p] = rr[k];
    }
  }
  __syncthreads();

  #pragma unroll
  for (int k = 0; k < 5; ++k){
    int i = t + k * 512;
    if (i < n) rec[e0 + i] = srec[i];
  }
  if (t < 128){
    int node = b * 128 + t;
    if (node < TN){
      startp[node] = (int)e0 + ex5[t];
      cntp[node] = cnt5[t];
    }
  }
}

// ---- layer-1 aggregation: one wave per node, 16 edges in flight ----
__global__ __launch_bounds__(256) void k_gather(const int* __restrict__ startp, const int* __restrict__ cntp,
                                                const int2* __restrict__ rec,
                                                const unsigned short* __restrict__ xb, unsigned short* __restrict__ zb){
  int wid = threadIdx.x >> 6, lane = threadIdx.x & 63;
  int node = blockIdx.x * 4 + wid;
  int e0 = startp[node], e1 = e0 + cntp[node];
  int g  = lane >> 4;
  int sl = lane & 15;
  const uint4* xp = (const uint4*)xb;

  float acc[8] = {0,0,0,0,0,0,0,0};

  #define FMA8(P, W)                                                          \
    acc[0] += (W) * __uint_as_float((P).x << 16);                             \
    acc[1] += (W) * __uint_as_float((P).x & 0xFFFF0000u);                     \
    acc[2] += (W) * __uint_as_float((P).y << 16);                             \
    acc[3] += (W) * __uint_as_float((P).y & 0xFFFF0000u);                     \
    acc[4] += (W) * __uint_as_float((P).z << 16);                             \
    acc[5] += (W) * __uint_as_float((P).z & 0xFFFF0000u);                     \
    acc[6] += (W) * __uint_as_float((P).w << 16);                             \
    acc[7] += (W) * __uint_as_float((P).w & 0xFFFF0000u);

  int e = e0;
  // 16 edges in flight: 4 rec loads, then 4 row loads, then FMAs
  for (; e + 16 <= e1; e += 16){
    int2 r0 = rec[e + g];
    int2 r1 = rec[e + 4 + g];
    int2 r2 = rec[e + 8 + g];
    int2 r3 = rec[e + 12 + g];
    uint4 p0 = xp[(size_t)(r0.x & 0x1FFFF) * 16 + sl];
    uint4 p1 = xp[(size_t)(r1.x & 0x1FFFF) * 16 + sl];
    uint4 p2 = xp[(size_t)(r2.x & 0x1FFFF) * 16 + sl];
    uint4 p3 = xp[(size_t)(r3.x & 0x1FFFF) * 16 + sl];
    float w0 = __int_as_float(r0.y);
    float w1 = __int_as_float(r1.y);
    float w2 = __int_as_float(r2.y);
    float w3 = __int_as_float(r3.y);
    FMA8(p0, w0)
    FMA8(p1, w1)
    FMA8(p2, w2)
    FMA8(p3, w3)
  }
  for (; e + 8 <= e1; e += 8){
    int2 r0 = rec[e + g];
    int2 r1 = rec[e + 4 + g];
    uint4 p0 = xp[(size_t)(r0.x & 0x1FFFF) * 16 + sl];
    uint4 p1 = xp[(size_t)(r1.x & 0x1FFFF) * 16 + sl];
    float w0 = __int_as_float(r0.y);
    float w1 = __int_as_float(r1.y);
    FMA8(p0, w0)
    FMA8(p1, w1)
  }
  if (e < e1){
    int ee = e + g;
    bool v0 = ee < e1;
    int2 r0 = rec[v0 ? ee : e0];
    int ee1 = e + 4 + g;
    bool v1 = ee1 < e1;
    int2 r1 = rec[v1 ? ee1 : e0];
    uint4 p0 = xp[(size_t)(r0.x & 0x1FFFF) * 16 + sl];
    uint4 p1 = xp[(size_t)(r1.x & 0x1FFFF) * 16 + sl];
    float w0 = v0 ? __int_as_float(r0.y) : 0.f;
    float w1 = v1 ? __int_as_float(r1.y) : 0.f;
    FMA8(p0, w0)
    FMA8(p1, w1)
  }
  #undef FMA8

  #pragma unroll
  for (int o = 16; o <= 32; o <<= 1){
    #pragma unroll
    for (int i = 0; i < 8; ++i) acc[i] += __shfl_xor(acc[i], o);
  }
  if (g == 0){
    uint4 o4;
    o4.x = ((unsigned)f2bf(acc[1]) << 16) | (unsigned)f2bf(acc[0]);
    o4.y = ((unsigned)f2bf(acc[3]) << 16) | (unsigned)f2bf(acc[2]);
    o4.z = ((unsigned)f2bf(acc[5]) << 16) | (unsigned)f2bf(acc[4]);
    o4.w = ((unsigned)f2bf(acc[7]) << 16) | (unsigned)f2bf(acc[6]);
    ((uint4*)zb)[(size_t)node * 16 + sl] = o4;
  }
}

// Fused: h = relu(z@W1^T + x@W2^T + b); u = h.crel; v = h.croot
// wave handles 32 nodes (2 tiles); weight fragments reused across both tiles
__global__ __launch_bounds__(256) void k_node(const unsigned short* __restrict__ zb, const unsigned short* __restrict__ xb,
    const unsigned short* __restrict__ W1b, const unsigned short* __restrict__ W2b,
    const float* __restrict__ brel1, const float* __restrict__ crel, const float* __restrict__ croot,
    float* __restrict__ u, float* __restrict__ v){
  int wid = threadIdx.x >> 6;
  int lane = threadIdx.x & 63;
  int l15 = lane & 15;
  int g4 = lane >> 4;
  int nb = blockIdx.x * 128 + wid * 32;

  short8 az[2][4], ax[2][4];
  #pragma unroll
  for (int nt = 0; nt < 2; ++nt){
    const unsigned short* zrow = zb + (size_t)(nb + nt * 16 + l15) * HD + g4 * 8;
    const unsigned short* xrow = xb + (size_t)(nb + nt * 16 + l15) * HD + g4 * 8;
    #pragma unroll
    for (int kk = 0; kk < 4; ++kk){
      az[nt][kk] = *(const short8*)(zrow + kk * 32);
      ax[nt][kk] = *(const short8*)(xrow + kk * 32);
    }
  }

  float usum[2][4] = {{0,0,0,0},{0,0,0,0}}, vsum[2][4] = {{0,0,0,0},{0,0,0,0}};
  #pragma unroll
  for (int t = 0; t < 8; ++t){
    int kcol = t * 16 + l15;
    const unsigned short* w1r = W1b + (size_t)kcol * HD + g4 * 8;
    const unsigned short* w2r = W2b + (size_t)kcol * HD + g4 * 8;
    short8 w1f[4], w2f[4];
    #pragma unroll
    for (int kk = 0; kk < 4; ++kk){
      w1f[kk] = *(const short8*)(w1r + kk * 32);
      w2f[kk] = *(const short8*)(w2r + kk * 32);
    }
    float bias = brel1[kcol], cr = crel[kcol], co = croot[kcol];
    #pragma unroll
    for (int nt = 0; nt < 2; ++nt){
      f32x4 acc = {0.f, 0.f, 0.f, 0.f};
      #pragma unroll
      for (int kk = 0; kk < 4; ++kk)
        acc = __builtin_amdgcn_mfma_f32_16x16x32_bf16(az[nt][kk], w1f[kk], acc, 0, 0, 0);
      #pragma unroll
      for (int kk = 0; kk < 4; ++kk)
        acc = __builtin_amdgcn_mfma_f32_16x16x32_bf16(ax[nt][kk], w2f[kk], acc, 0, 0, 0);
      #pragma unroll
      for (int r = 0; r < 4; ++r){
        float h = fmaxf(acc[r] + bias, 0.f);
        usum[nt][r] += h * cr;
        vsum[nt][r] += h * co;
      }
    }
  }
  #pragma unroll
  for (int o = 1; o < 16; o <<= 1){
    #pragma unroll
    for (int nt = 0; nt < 2; ++nt){
      #pragma unroll
      for (int r = 0; r < 4; ++r){
        usum[nt][r] += __shfl_xor(usum[nt][r], o);
        vsum[nt][r] += __shfl_xor(vsum[nt][r], o);
      }
    }
  }
  if (l15 == 0){
    #pragma unroll
    for (int nt = 0; nt < 2; ++nt){
      #pragma unroll
      for (int r = 0; r < 4; ++r){
        int node = nb + nt * 16 + g4 * 4 + r;
        u[node] = usum[nt][r];
        v[node] = vsum[nt][r];
      }
    }
  }
}

// ---- layer-2 collapsed aggregation: thread per node, dual-load unroll ----
__global__ __launch_bounds__(256) void k_pool2(const int* __restrict__ startp, const int* __restrict__ cntp,
                                               const int2* __restrict__ rec,
                                               const float* __restrict__ u, float* __restrict__ sacc){
  int i = blockIdx.x * 256 + threadIdx.x;
  if (i >= TN) return;
  if (i % NPG >= NG) return;     // never read by k_final
  int e0 = startp[i], e1 = e0 + cntp[i];
  float s = 0.f;
  int e = e0;
  for (; e + 2 <= e1; e += 2){
    int2 r0 = rec[e];
    int2 r1 = rec[e + 1];
    float u0 = u[r0.x & 0x1FFFF];
    float u1 = u[r1.x & 0x1FFFF];
    s += __int_as_float(r0.y) * u0 + __int_as_float(r1.y) * u1;
  }
  if (e < e1){
    int2 r = rec[e];
    s += __int_as_float(r.y) * u[r.x & 0x1FFFF];
  }
  sacc[i] = s;
}

// generic block reduction for 1024 threads (16 waves)
__device__ __forceinline__ float blk_red_add16(float x, float* red){
  #pragma unroll
  for (int o = 32; o > 0; o >>= 1) x += __shfl_xor(x, o);
  int wid = threadIdx.x >> 6, lane = threadIdx.x & 63;
  __syncthreads();
  if (lane == 0) red[wid] = x;
  __syncthreads();
  float s = 0.f;
  #pragma unroll
  for (int j = 0; j < 16; ++j) s += red[j];
  return s;
}
__device__ __forceinline__ float blk_red_max16(float x, float* red){
  #pragma unroll
  for (int o = 32; o > 0; o >>= 1) x = fmaxf(x, __shfl_xor(x, o));
  int wid = threadIdx.x >> 6, lane = threadIdx.x & 63;
  __syncthreads();
  if (lane == 0) red[wid] = x;
  __syncthreads();
  float s = red[0];
  #pragma unroll
  for (int j = 1; j < 16; ++j) s = fmaxf(s, red[j]);
  return s;
}

__global__ __launch_bounds__(1024) void k_final(const float* __restrict__ s, const float* __restrict__ vv,
    const float* __restrict__ cbp, const float* __restrict__ gamma, const float* __restrict__ beta,
    float* __restrict__ out){
  __shared__ float t[NG];
  __shared__ float red[16];
  int b = blockIdx.x, tid = threadIdx.x;
  float cb = cbp[0];
  const float inv = 1.f / (float)HD;
  float lsum = 0.f, lsq = 0.f;
  for (int j = tid; j < NG; j += 1024){
    float g = (s[b*NPG + j] + vv[b*NPG + j] + cb) * inv;
    t[j] = g; lsum += g; lsq += g * g;
  }
  float S1 = blk_red_add16(lsum, red);
  float S2 = blk_red_add16(lsq, red);
  float mu = S1 / (float)NG;
  float var = S2 / (float)NG - mu * mu;
  float rstd = rsqrtf(var + 1e-5f);
  float lmax = -3.4e38f;
  for (int j = tid; j < NG; j += 1024){
    float tj = (t[j] - mu) * rstd * gamma[j] + beta[j];
    t[j] = tj; lmax = fmaxf(lmax, tj);
  }
  float M = blk_red_max16(lmax, red);
  float lexp = 0.f;
  for (int j = tid; j < NG; j += 1024) lexp += expf(t[j] - M);
  float S = blk_red_add16(lexp, red);
  float lse = M + logf(S);
  for (int j = tid; j < NG; j += 1024) out[b*NG + j] = t[j] - lse;
}

extern "C" void kernel_launch(void* const* d_in, const int* in_sizes, int n_in,
                              void* d_out, int out_size, void* d_ws, size_t ws_size,
                              hipStream_t stream){
  const float* x      = (const float*)d_in[0];
  const int*   ei     = (const int*)d_in[1];
  const float* ew     = (const float*)d_in[3];
  const float* Wrel1  = (const float*)d_in[4];
  const float* brel1  = (const float*)d_in[5];
  const float* Wroot1 = (const float*)d_in[6];
  const float* Wrel2  = (const float*)d_in[7];
  const float* brel2  = (const float*)d_in[8];
  const float* Wroot2 = (const float*)d_in[9];
  const float* gamma  = (const float*)d_in[10];
  const float* beta   = (const float*)d_in[11];
  const int*   src    = ei;
  const int*   dst    = ei + NE;

  char* ws = (char*)d_ws;
  size_t off_b = 0;
  auto alloc = [&](size_t bytes) -> char* {
    char* p = ws + off_b;
    off_b += (bytes + 511) & ~(size_t)511;
    return p;
  };
  unsigned short* xb    = (unsigned short*)alloc((size_t)TN * HD * 2);
  unsigned short* zb    = (unsigned short*)alloc((size_t)TN * HD * 2);
  unsigned short* W1b   = (unsigned short*)alloc(HD * HD * 2);
  unsigned short* W2b   = (unsigned short*)alloc(HD * HD * 2);
  float*          crel  = (float*)alloc(HD * 4);
  float*          croot = (float*)alloc(HD * 4);
  float*          cbp   = (float*)alloc(4);
  float*          u     = (float*)alloc(TN * 4);
  float*          v     = (float*)alloc(TN * 4);
  float*          sacc  = (float*)alloc(TN * 4);
  int*            startp= (int*)alloc(TN * 4);
  int*            cntp  = (int*)alloc(TN * 4);
  int*            gcur  = (int*)alloc(NBUCK * 4);
  int2*           rec   = (int2*)alloc((size_t)NBUCK * BCAP * 8);

  hipMemsetAsync(gcur, 0, NBUCK * 4, stream);

  k_prepbin<<<NCHUNK + 1 + PX_BLK + PW_BLK, 512, 0, stream>>>(
      Wrel2, Wroot2, brel2, crel, croot, cbp,
      src, dst, ew, gcur, rec,
      x, xb, Wrel1, Wroot1, W1b, W2b);
  k_nsort <<<NBUCK, 512, 0, stream>>>(gcur, rec, startp, cntp);
  k_gather<<<TN/4, 256, 0, stream>>>(startp, cntp, rec, xb, zb);
  k_node  <<<TN/128, 256, 0, stream>>>(zb, xb, W1b, W2b, brel1, crel, croot, u, v);
  k_pool2 <<<(TN+255)/256, 256, 0, stream>>>(startp, cntp, rec, u, sacc);
  k_final <<<NB, 1024, 0, stream>>>(sacc, v, cbp, gamma, beta, (float*)d_out);
}

// Round 15
// 114.303 us; speedup vs baseline: 1.6676x; 1.1866x over previous
//
#include <hip/hip_runtime.h>

#define TN 80000
#define HD 128
#define NE 1280000
#define NB 8
#define NPG 10000
#define NG 8000

#define NBUCK 625           // buckets of 128 nodes (dst>>7)
#define BCAP  2304          // per-bucket record capacity (avg 2048)
#define CHUNK 4096
#define NCHUNK ((NE + CHUNK - 1) / CHUNK)   // 313

#define PX_BLK 2500         // x->bf16: 2500 blocks x 512 thr x 8 elems
#define PW_BLK 32           // weights->bf16: 16384 elems / 512

typedef __attribute__((ext_vector_type(8))) short short8;
typedef __attribute__((ext_vector_type(4))) float f32x4;

__device__ __forceinline__ unsigned short f2bf(float f){
  unsigned int u = __float_as_uint(f);
  u = u + 0x7FFFu + ((u >> 16) & 1u);
  return (unsigned short)(u >> 16);
}

__device__ __forceinline__ short8 pack_bf8(float4 a, float4 b){
  short8 o;
  o[0] = (short)f2bf(a.x); o[1] = (short)f2bf(a.y); o[2] = (short)f2bf(a.z); o[3] = (short)f2bf(a.w);
  o[4] = (short)f2bf(b.x); o[5] = (short)f2bf(b.y); o[6] = (short)f2bf(b.z); o[7] = (short)f2bf(b.w);
  return o;
}

// blocks [0,NCHUNK): chunk-sort edges by bucket (dst>>7) ; NCHUNK: colsums ;
// rest: x->bf16 and W->bf16 conversions (independent work, overlaps cbin)
// record: word0 = src | (dst&127)<<17 ; word1 = weight f32
__global__ __launch_bounds__(512) void k_prepbin(
    const float* __restrict__ Wrel2, const float* __restrict__ Wroot2, const float* __restrict__ brel2,
    float* __restrict__ crel, float* __restrict__ croot, float* __restrict__ cb,
    const int* __restrict__ src, const int* __restrict__ dst, const float* __restrict__ ew,
    int* __restrict__ gcur, int2* __restrict__ rec,
    const float* __restrict__ x, unsigned short* __restrict__ xb,
    const float* __restrict__ W1, const float* __restrict__ W2,
    unsigned short* __restrict__ W1b, unsigned short* __restrict__ W2b){
  int b = blockIdx.x;
  int t = threadIdx.x;
  if (b >= NCHUNK){
    if (b == NCHUNK){
      int k = t;
      if (k < HD){
        float a = 0.f, c = 0.f;
        for (int f = 0; f < HD; ++f){ a += Wrel2[f*HD + k]; c += Wroot2[f*HD + k]; }
        crel[k] = a; croot[k] = c;
        if (k == 0){ float s = 0.f; for (int f = 0; f < HD; ++f) s += brel2[f]; cb[0] = s; }
      }
      return;
    }
    int cb2 = b - NCHUNK - 1;
    if (cb2 < PX_BLK){
      size_t i = ((size_t)cb2 * 512 + t) * 8;
      float4 a0 = *(const float4*)(x + i), a1 = *(const float4*)(x + i + 4);
      *(short8*)(xb + i) = pack_bf8(a0, a1);
    } else {
      int i = (cb2 - PX_BLK) * 512 + t;
      W1b[i] = f2bf(W1[i]);
      W2b[i] = f2bf(W2[i]);
    }
    return;
  }
  // ---- cbin ----
  __shared__ int h[640];
  __shared__ int ex[640];
  __shared__ int2 grec[CHUNK];          // 32 KB
  __shared__ unsigned short gcb[CHUNK]; // 8 KB
  int base = b * CHUNK;
  int n = NE - base; if (n > CHUNK) n = CHUNK;

  for (int i = t; i < 640; i += 512) h[i] = 0;
  __syncthreads();

  int pa[8]; float pw[8]; int pc[8];
  #pragma unroll
  for (int k = 0; k < 8; ++k){
    int idx = t + k * 512;
    if (idx < n){
      int e = base + idx;
      int d = dst[e];
      int cbk = d >> 7;
      pa[k] = src[e] | ((d & 127) << 17);
      pw[k] = ew[e];
      pc[k] = cbk;
      atomicAdd(&h[cbk], 1);
    } else pc[k] = -1;
  }
  __syncthreads();

  if (t < 64){
    int b0 = t * 10;
    int s = 0;
    #pragma unroll
    for (int j = 0; j < 10; ++j) s += h[b0 + j];
    int v = s;
    #pragma unroll
    for (int o = 1; o < 64; o <<= 1){ int q = __shfl_up(v, o); if (t >= o) v += q; }
    int run = v - s;
    #pragma unroll
    for (int j = 0; j < 10; ++j){ int q = h[b0 + j]; h[b0 + j] = run; ex[b0 + j] = run; run += q; }
  }
  __syncthreads();

  #pragma unroll
  for (int k = 0; k < 8; ++k){
    if (pc[k] >= 0){
      int p = atomicAdd(&h[pc[k]], 1);
      grec[p] = make_int2(pa[k], __float_as_int(pw[k]));
      gcb[p] = (unsigned short)pc[k];
    }
  }
  __syncthreads();

  for (int i = t; i < NBUCK; i += 512){
    int cnt = h[i] - ex[i];
    int go = 0;
    if (cnt > 0) go = atomicAdd(&gcur[i], cnt);
    ex[i] = i * BCAP + go - ex[i];
  }
  __syncthreads();

  for (int p = t; p < n; p += 512){
    int cbk = gcb[p];
    int ga = ex[cbk] + p;
    if (ga < (cbk + 1) * BCAP) rec[ga] = grec[p];
  }
}

// pure nsort: per-bucket counting sort by node (7-bit local id) -> start/cnt
__global__ __launch_bounds__(512) void k_nsort(const int* __restrict__ gcur, int2* __restrict__ rec,
                                               int* __restrict__ startp, int* __restrict__ cntp){
  __shared__ int cnt5[128], ex5[128], cur5[128];
  __shared__ int2 srec[BCAP];          // ~18.4 KB
  int t = threadIdx.x, b = blockIdx.x;
  int n = gcur[b]; if (n > BCAP) n = BCAP;
  size_t e0 = (size_t)b * BCAP;
  if (t < 128) cnt5[t] = 0;
  __syncthreads();

  int2 rr[5];
  #pragma unroll
  for (int k = 0; k < 5; ++k){
    int i = t + k * 512;
    if (i < n){
      rr[k] = rec[e0 + i];
      atomicAdd(&cnt5[(rr[k].x >> 17) & 127], 1);
    }
  }
  __syncthreads();

  if (t < 64){
    int b0 = t * 2;
    int s = cnt5[b0] + cnt5[b0 + 1];
    int v = s;
    #pragma unroll
    for (int o = 1; o < 64; o <<= 1){ int q = __shfl_up(v, o); if (t >= o) v += q; }
    int run = v - s;
    int q0 = cnt5[b0];
    ex5[b0] = run; cur5[b0] = run;
    ex5[b0 + 1] = run + q0; cur5[b0 + 1] = run + q0;
  }
  __syncthreads();

  #pragma unroll
  for (int k = 0; k < 5; ++k){
    int i = t + k * 512;
    if (i < n){
      int p = atomicAdd(&cur5[(rr[k].x >> 17) & 127], 1);
      srec[p] = rr[k];
    }
  }
  __syncthreads();

  #pragma unroll
  for (int k = 0; k < 5; ++k){
    int i = t + k * 512;
    if (i < n) rec[e0 + i] = srec[i];
  }
  if (t < 128){
    int node = b * 128 + t;
    if (node < TN){
      startp[node] = (int)e0 + ex5[t];
      cntp[node] = cnt5[t];
    }
  }
}

// ---- layer-1 aggregation: one wave per node, 16 edges in flight ----
__global__ __launch_bounds__(256) void k_gather(const int* __restrict__ startp, const int* __restrict__ cntp,
                                                const int2* __restrict__ rec,
                                                const unsigned short* __restrict__ xb, unsigned short* __restrict__ zb){
  int wid = threadIdx.x >> 6, lane = threadIdx.x & 63;
  int node = blockIdx.x * 4 + wid;
  int e0 = startp[node], e1 = e0 + cntp[node];
  int g  = lane >> 4;
  int sl = lane & 15;
  const uint4* xp = (const uint4*)xb;

  float acc[8] = {0,0,0,0,0,0,0,0};

  #define FMA8(P, W)                                                          \
    acc[0] += (W) * __uint_as_float((P).x << 16);                             \
    acc[1] += (W) * __uint_as_float((P).x & 0xFFFF0000u);                     \
    acc[2] += (W) * __uint_as_float((P).y << 16);                             \
    acc[3] += (W) * __uint_as_float((P).y & 0xFFFF0000u);                     \
    acc[4] += (W) * __uint_as_float((P).z << 16);                             \
    acc[5] += (W) * __uint_as_float((P).z & 0xFFFF0000u);                     \
    acc[6] += (W) * __uint_as_float((P).w << 16);                             \
    acc[7] += (W) * __uint_as_float((P).w & 0xFFFF0000u);

  int e = e0;
  for (; e + 16 <= e1; e += 16){
    int2 r0 = rec[e + g];
    int2 r1 = rec[e + 4 + g];
    int2 r2 = rec[e + 8 + g];
    int2 r3 = rec[e + 12 + g];
    uint4 p0 = xp[(size_t)(r0.x & 0x1FFFF) * 16 + sl];
    uint4 p1 = xp[(size_t)(r1.x & 0x1FFFF) * 16 + sl];
    uint4 p2 = xp[(size_t)(r2.x & 0x1FFFF) * 16 + sl];
    uint4 p3 = xp[(size_t)(r3.x & 0x1FFFF) * 16 + sl];
    float w0 = __int_as_float(r0.y);
    float w1 = __int_as_float(r1.y);
    float w2 = __int_as_float(r2.y);
    float w3 = __int_as_float(r3.y);
    FMA8(p0, w0)
    FMA8(p1, w1)
    FMA8(p2, w2)
    FMA8(p3, w3)
  }
  for (; e + 8 <= e1; e += 8){
    int2 r0 = rec[e + g];
    int2 r1 = rec[e + 4 + g];
    uint4 p0 = xp[(size_t)(r0.x & 0x1FFFF) * 16 + sl];
    uint4 p1 = xp[(size_t)(r1.x & 0x1FFFF) * 16 + sl];
    float w0 = __int_as_float(r0.y);
    float w1 = __int_as_float(r1.y);
    FMA8(p0, w0)
    FMA8(p1, w1)
  }
  if (e < e1){
    int ee = e + g;
    bool v0 = ee < e1;
    int2 r0 = rec[v0 ? ee : e0];
    int ee1 = e + 4 + g;
    bool v1 = ee1 < e1;
    int2 r1 = rec[v1 ? ee1 : e0];
    uint4 p0 = xp[(size_t)(r0.x & 0x1FFFF) * 16 + sl];
    uint4 p1 = xp[(size_t)(r1.x & 0x1FFFF) * 16 + sl];
    float w0 = v0 ? __int_as_float(r0.y) : 0.f;
    float w1 = v1 ? __int_as_float(r1.y) : 0.f;
    FMA8(p0, w0)
    FMA8(p1, w1)
  }
  #undef FMA8

  #pragma unroll
  for (int o = 16; o <= 32; o <<= 1){
    #pragma unroll
    for (int i = 0; i < 8; ++i) acc[i] += __shfl_xor(acc[i], o);
  }
  if (g == 0){
    uint4 o4;
    o4.x = ((unsigned)f2bf(acc[1]) << 16) | (unsigned)f2bf(acc[0]);
    o4.y = ((unsigned)f2bf(acc[3]) << 16) | (unsigned)f2bf(acc[2]);
    o4.z = ((unsigned)f2bf(acc[5]) << 16) | (unsigned)f2bf(acc[4]);
    o4.w = ((unsigned)f2bf(acc[7]) << 16) | (unsigned)f2bf(acc[6]);
    ((uint4*)zb)[(size_t)node * 16 + sl] = o4;
  }
}

// Fused: h = relu(z@W1^T + x@W2^T + b); u = h.crel; v = h.croot
// weights staged in LDS once per block (slot-major layout: conflict-free
// stores [consecutive lanes -> consecutive kcol -> +16B] and conflict-free
// ds_read_b128 in the MFMA loop [16 lanes -> consecutive kcol]).
__global__ __launch_bounds__(256) void k_node(const unsigned short* __restrict__ zb, const unsigned short* __restrict__ xb,
    const unsigned short* __restrict__ W1b, const unsigned short* __restrict__ W2b,
    const float* __restrict__ brel1, const float* __restrict__ crel, const float* __restrict__ croot,
    float* __restrict__ u, float* __restrict__ v){
  __shared__ unsigned short Wl[2][16 * 128 * 8];   // 2 x 32 KB, [mat][(slot*128+kcol)*8+j]
  int tid = threadIdx.x;
  int wid = tid >> 6;
  int lane = tid & 63;
  int l15 = lane & 15;
  int g4 = lane >> 4;
  int nb = blockIdx.x * 128 + wid * 32;

  // stage weights: slot = (kk*4+g4), d0 = kk*32+g4*8 = (slot>>2)*32+(slot&3)*8
  #pragma unroll
  for (int it = 0; it < 8; ++it){
    int slot = it * 2 + (tid >> 7);
    int kcol = tid & 127;
    int d0 = ((slot >> 2) << 5) + ((slot & 3) << 3);
    *(uint4*)&Wl[0][(slot * 128 + kcol) * 8] = *(const uint4*)&W1b[kcol * 128 + d0];
    *(uint4*)&Wl[1][(slot * 128 + kcol) * 8] = *(const uint4*)&W2b[kcol * 128 + d0];
  }

  short8 az[2][4], ax[2][4];
  #pragma unroll
  for (int nt = 0; nt < 2; ++nt){
    const unsigned short* zrow = zb + (size_t)(nb + nt * 16 + l15) * HD + g4 * 8;
    const unsigned short* xrow = xb + (size_t)(nb + nt * 16 + l15) * HD + g4 * 8;
    #pragma unroll
    for (int kk = 0; kk < 4; ++kk){
      az[nt][kk] = *(const short8*)(zrow + kk * 32);
      ax[nt][kk] = *(const short8*)(xrow + kk * 32);
    }
  }
  __syncthreads();

  float usum[2][4] = {{0,0,0,0},{0,0,0,0}}, vsum[2][4] = {{0,0,0,0},{0,0,0,0}};
  #pragma unroll
  for (int t = 0; t < 8; ++t){
    int kcol = t * 16 + l15;
    short8 w1f[4], w2f[4];
    #pragma unroll
    for (int kk = 0; kk < 4; ++kk){
      int slot = (kk << 2) | g4;
      w1f[kk] = *(const short8*)&Wl[0][(slot * 128 + kcol) * 8];
      w2f[kk] = *(const short8*)&Wl[1][(slot * 128 + kcol) * 8];
    }
    float bias = brel1[kcol], cr = crel[kcol], co = croot[kcol];
    #pragma unroll
    for (int nt = 0; nt < 2; ++nt){
      f32x4 acc = {0.f, 0.f, 0.f, 0.f};
      #pragma unroll
      for (int kk = 0; kk < 4; ++kk)
        acc = __builtin_amdgcn_mfma_f32_16x16x32_bf16(az[nt][kk], w1f[kk], acc, 0, 0, 0);
      #pragma unroll
      for (int kk = 0; kk < 4; ++kk)
        acc = __builtin_amdgcn_mfma_f32_16x16x32_bf16(ax[nt][kk], w2f[kk], acc, 0, 0, 0);
      #pragma unroll
      for (int r = 0; r < 4; ++r){
        float h = fmaxf(acc[r] + bias, 0.f);
        usum[nt][r] += h * cr;
        vsum[nt][r] += h * co;
      }
    }
  }
  #pragma unroll
  for (int o = 1; o < 16; o <<= 1){
    #pragma unroll
    for (int nt = 0; nt < 2; ++nt){
      #pragma unroll
      for (int r = 0; r < 4; ++r){
        usum[nt][r] += __shfl_xor(usum[nt][r], o);
        vsum[nt][r] += __shfl_xor(vsum[nt][r], o);
      }
    }
  }
  if (l15 == 0){
    #pragma unroll
    for (int nt = 0; nt < 2; ++nt){
      #pragma unroll
      for (int r = 0; r < 4; ++r){
        int node = nb + nt * 16 + g4 * 4 + r;
        u[node] = usum[nt][r];
        v[node] = vsum[nt][r];
      }
    }
  }
}

// ---- layer-2 collapsed aggregation: 16 lanes per node (coalesced rec reads) ----
__global__ __launch_bounds__(256) void k_pool2(const int* __restrict__ startp, const int* __restrict__ cntp,
                                               const int2* __restrict__ rec,
                                               const float* __restrict__ u, float* __restrict__ sacc){
  int t = threadIdx.x;
  int sg = t >> 4;          // 16 node-subgroups per block
  int li = t & 15;
  int node = blockIdx.x * 16 + sg;
  if (node >= TN) return;
  if (node % NPG >= NG) return;   // never read by k_final
  int e0 = startp[node], cnt = cntp[node];
  float s = 0.f;
  for (int i = li; i < cnt; i += 16){
    int2 r = rec[e0 + i];
    s += __int_as_float(r.y) * u[r.x & 0x1FFFF];
  }
  #pragma unroll
  for (int o = 1; o < 16; o <<= 1) s += __shfl_xor(s, o);
  if (li == 0) sacc[node] = s;
}

// generic block reduction for 1024 threads (16 waves)
__device__ __forceinline__ float blk_red_add16(float x, float* red){
  #pragma unroll
  for (int o = 32; o > 0; o >>= 1) x += __shfl_xor(x, o);
  int wid = threadIdx.x >> 6, lane = threadIdx.x & 63;
  __syncthreads();
  if (lane == 0) red[wid] = x;
  __syncthreads();
  float s = 0.f;
  #pragma unroll
  for (int j = 0; j < 16; ++j) s += red[j];
  return s;
}
__device__ __forceinline__ float blk_red_max16(float x, float* red){
  #pragma unroll
  for (int o = 32; o > 0; o >>= 1) x = fmaxf(x, __shfl_xor(x, o));
  int wid = threadIdx.x >> 6, lane = threadIdx.x & 63;
  __syncthreads();
  if (lane == 0) red[wid] = x;
  __syncthreads();
  float s = red[0];
  #pragma unroll
  for (int j = 1; j < 16; ++j) s = fmaxf(s, red[j]);
  return s;
}

__global__ __launch_bounds__(1024) void k_final(const float* __restrict__ s, const float* __restrict__ vv,
    const float* __restrict__ cbp, const float* __restrict__ gamma, const float* __restrict__ beta,
    float* __restrict__ out){
  __shared__ float t[NG];
  __shared__ float red[16];
  int b = blockIdx.x, tid = threadIdx.x;
  float cb = cbp[0];
  const float inv = 1.f / (float)HD;
  float lsum = 0.f, lsq = 0.f;
  for (int j = tid; j < NG; j += 1024){
    float g = (s[b*NPG + j] + vv[b*NPG + j] + cb) * inv;
    t[j] = g; lsum += g; lsq += g * g;
  }
  float S1 = blk_red_add16(lsum, red);
  float S2 = blk_red_add16(lsq, red);
  float mu = S1 / (float)NG;
  float var = S2 / (float)NG - mu * mu;
  float rstd = rsqrtf(var + 1e-5f);
  float lmax = -3.4e38f;
  for (int j = tid; j < NG; j += 1024){
    float tj = (t[j] - mu) * rstd * gamma[j] + beta[j];
    t[j] = tj; lmax = fmaxf(lmax, tj);
  }
  float M = blk_red_max16(lmax, red);
  float lexp = 0.f;
  for (int j = tid; j < NG; j += 1024) lexp += expf(t[j] - M);
  float S = blk_red_add16(lexp, red);
  float lse = M + logf(S);
  for (int j = tid; j < NG; j += 1024) out[b*NG + j] = t[j] - lse;
}

extern "C" void kernel_launch(void* const* d_in, const int* in_sizes, int n_in,
                              void* d_out, int out_size, void* d_ws, size_t ws_size,
                              hipStream_t stream){
  const float* x      = (const float*)d_in[0];
  const int*   ei     = (const int*)d_in[1];
  const float* ew     = (const float*)d_in[3];
  const float* Wrel1  = (const float*)d_in[4];
  const float* brel1  = (const float*)d_in[5];
  const float* Wroot1 = (const float*)d_in[6];
  const float* Wrel2  = (const float*)d_in[7];
  const float* brel2  = (const float*)d_in[8];
  const float* Wroot2 = (const float*)d_in[9];
  const float* gamma  = (const float*)d_in[10];
  const float* beta   = (const float*)d_in[11];
  const int*   src    = ei;
  const int*   dst    = ei + NE;

  char* ws = (char*)d_ws;
  size_t off_b = 0;
  auto alloc = [&](size_t bytes) -> char* {
    char* p = ws + off_b;
    off_b += (bytes + 511) & ~(size_t)511;
    return p;
  };
  unsigned short* xb    = (unsigned short*)alloc((size_t)TN * HD * 2);
  unsigned short* zb    = (unsigned short*)alloc((size_t)TN * HD * 2);
  unsigned short* W1b   = (unsigned short*)alloc(HD * HD * 2);
  unsigned short* W2b   = (unsigned short*)alloc(HD * HD * 2);
  float*          crel  = (float*)alloc(HD * 4);
  float*          croot = (float*)alloc(HD * 4);
  float*          cbp   = (float*)alloc(4);
  float*          u     = (float*)alloc(TN * 4);
  float*          v     = (float*)alloc(TN * 4);
  float*          sacc  = (float*)alloc(TN * 4);
  int*            startp= (int*)alloc(TN * 4);
  int*            cntp  = (int*)alloc(TN * 4);
  int*            gcur  = (int*)alloc(NBUCK * 4);
  int2*           rec   = (int2*)alloc((size_t)NBUCK * BCAP * 8);

  hipMemsetAsync(gcur, 0, NBUCK * 4, stream);

  k_prepbin<<<NCHUNK + 1 + PX_BLK + PW_BLK, 512, 0, stream>>>(
      Wrel2, Wroot2, brel2, crel, croot, cbp,
      src, dst, ew, gcur, rec,
      x, xb, Wrel1, Wroot1, W1b, W2b);
  k_nsort <<<NBUCK, 512, 0, stream>>>(gcur, rec, startp, cntp);
  k_gather<<<TN/4, 256, 0, stream>>>(startp, cntp, rec, xb, zb);
  k_node  <<<TN/128, 256, 0, stream>>>(zb, xb, W1b, W2b, brel1, crel, croot, u, v);
  k_pool2 <<<(TN+15)/16, 256, 0, stream>>>(startp, cntp, rec, u, sacc);
  k_final <<<NB, 1024, 0, stream>>>(sacc, v, cbp, gamma, beta, (float*)d_out);
}